// Round 1
// baseline (344.678 us; speedup 1.0000x reference)
//
#include <hip/hip_runtime.h>
#include <math.h>

// Problem constants (match reference)
#define B_  8
#define L_  4096
#define D_  768
#define NC_ 4096
#define M_  (B_*NC_)   // 32768 chunk-rows total

// ---------------------------------------------------------------------------
// ws layout:
//  [0]  float num   (sum of mask_regular_o)
//  [1]  float den   (sum of regular_tokens_mask)
//  byte 16:            int keep[NC_]
//  byte 16+NC_*4:      int counts[M_]
//  next:               int starts[M_]
// total ~ 280 KB
// ---------------------------------------------------------------------------

__device__ __forceinline__ int lower_bound(const int* __restrict__ a, int lo, int hi, int v) {
    while (lo < hi) {
        int mid = (lo + hi) >> 1;
        if (a[mid] < v) lo = mid + 1; else hi = mid;
    }
    return lo;
}

// Kernel 1: per (b,c) chunk metadata via binary search on sorted seg_ids.
// Writes counts/starts to ws, raw (pre-keep) masks as float into d_out,
// and accumulates denominator sum(regular_tokens_mask) = sum(count*mr).
__global__ void meta_kernel(const int* __restrict__ seg,
                            const int* __restrict__ padm,
                            const int* __restrict__ regm,
                            const int* __restrict__ spm,
                            int* __restrict__ counts, int* __restrict__ starts,
                            float* __restrict__ out_mp, float* __restrict__ out_mr,
                            float* __restrict__ out_sp, float* __restrict__ den) {
    int idx = blockIdx.x * blockDim.x + threadIdx.x;   // [0, M_)
    int b = idx >> 12;          // / NC_
    int c = idx & (NC_ - 1);
    const int* row = seg + b * L_;
    int s = lower_bound(row, 0, L_, c);
    int e = lower_bound(row, s, L_, c + 1);
    int cnt = e - s;
    counts[idx] = cnt;
    starts[idx] = s;
    // masks are chunk-constant by construction -> first element == any == all
    int mp = 0, mr = 0;
    if (cnt > 0) { mp = padm[b * L_ + s]; mr = regm[b * L_ + s]; }
    int sp = (mp == 0) ? -1 : spm[b * L_ + s];
    out_mp[idx] = (float)mp;
    out_mr[idx] = (float)mr;
    out_sp[idx] = (float)sp;
    // denominator: sum over tokens of regular_tokens_mask == sum cnt*mr
    float dcon = (float)(cnt * mr);
    #pragma unroll
    for (int off = 32; off; off >>= 1) dcon += __shfl_down(dcon, off);
    if ((threadIdx.x & 63) == 0) atomicAdd(den, dcon);
}

// Kernel 2: keep[c] = OR_b mask_padding; apply keep to the three masks in-place;
// accumulate numerator sum(mask_regular_o).
__global__ void keep_kernel(float* __restrict__ out_mp, float* __restrict__ out_mr,
                            float* __restrict__ out_sp,
                            int* __restrict__ keep, float* __restrict__ num) {
    int c = blockIdx.x * blockDim.x + threadIdx.x;   // [0, NC_)
    int k = 0;
    #pragma unroll
    for (int b = 0; b < B_; b++) if (out_mp[b * NC_ + c] > 0.5f) k = 1;
    keep[c] = k;
    float nm = 0.f;
    if (!k) {
        #pragma unroll
        for (int b = 0; b < B_; b++) {
            out_mp[b * NC_ + c] = 0.f;
            out_mr[b * NC_ + c] = 0.f;
            out_sp[b * NC_ + c] = 0.f;
        }
    } else {
        #pragma unroll
        for (int b = 0; b < B_; b++) nm += out_mr[b * NC_ + c];
    }
    #pragma unroll
    for (int off = 32; off; off >>= 1) nm += __shfl_down(nm, off);
    if ((threadIdx.x & 63) == 0) atomicAdd(num, nm);
}

// Kernel 3: per-chunk mean into d_out compact region (staging for in-place GEMM).
// One block per chunk-row; 256 threads x 3 columns.
__global__ void mean_kernel(const float* __restrict__ x,
                            const int* __restrict__ counts,
                            const int* __restrict__ starts,
                            float* __restrict__ out) {
    int m = blockIdx.x;           // [0, M_)
    int b = m >> 12;
    int cnt = counts[m];
    int s = starts[m];
    float* o = out + (size_t)m * D_;
    int t = threadIdx.x;
    float a0 = 0.f, a1 = 0.f, a2 = 0.f;
    if (cnt > 0) {
        const float* base = x + ((size_t)b * L_ + s) * D_;
        for (int tk = 0; tk < cnt; ++tk) {
            const float* p = base + (size_t)tk * D_;
            a0 += p[t]; a1 += p[t + 256]; a2 += p[t + 512];
        }
        float inv = 1.f / (float)cnt;
        a0 *= inv; a1 *= inv; a2 *= inv;
    }
    o[t] = a0; o[t + 256] = a1; o[t + 512] = a2;
}

// Kernel 4: in-place row-block GEMM + bias + tanh + activity masking.
// Each block owns BM full rows of the compact region: reads them into LDS,
// computes rows @ W (K=N=768), overwrites rows. Tiles with no active row
// (count==0 or keep==0 for all rows) write zeros and exit (c>=2048 half).
#define BM_ 16
__global__ __launch_bounds__(256) void gemm_tanh_kernel(
        float* __restrict__ out,                  // [M_][D_] in-place
        const float* __restrict__ Wm,             // [D_][D_]
        const float* __restrict__ bias,           // [D_]
        const int* __restrict__ counts,
        const int* __restrict__ keep) {
    __shared__ float sMean[BM_][D_];              // 48 KB
    __shared__ int sAct[BM_];
    int m0 = blockIdx.x * BM_;
    int t = threadIdx.x;
    if (t < BM_) {
        int m = m0 + t;
        int c = m & (NC_ - 1);
        sAct[t] = (counts[m] > 0) && keep[c];
    }
    __syncthreads();
    int any = 0;
    #pragma unroll
    for (int r = 0; r < BM_; r++) any |= sAct[r];
    int c0 = t, c1 = t + 256, c2 = t + 512;
    if (!any) {
        #pragma unroll
        for (int r = 0; r < BM_; r++) {
            float* o = out + (size_t)(m0 + r) * D_;
            o[c0] = 0.f; o[c1] = 0.f; o[c2] = 0.f;
        }
        return;
    }
    // stage the BM_ x D_ mean tile into LDS (float4, coalesced)
    {
        const float4* src = (const float4*)(out + (size_t)m0 * D_);
        float4* dst = (float4*)(&sMean[0][0]);
        #pragma unroll
        for (int i = 0; i < (BM_ * D_ / 4) / 256; ++i)
            dst[t + i * 256] = src[t + i * 256];
    }
    __syncthreads();

    float acc[BM_][3] = {};
    for (int k = 0; k < D_; k += 4) {
        const float* wr = Wm + (size_t)k * D_;
        float w00 = wr[c0],          w01 = wr[c1],          w02 = wr[c2];
        float w10 = wr[D_ + c0],     w11 = wr[D_ + c1],     w12 = wr[D_ + c2];
        float w20 = wr[2 * D_ + c0], w21 = wr[2 * D_ + c1], w22 = wr[2 * D_ + c2];
        float w30 = wr[3 * D_ + c0], w31 = wr[3 * D_ + c1], w32 = wr[3 * D_ + c2];
        #pragma unroll
        for (int r = 0; r < BM_; r++) {
            float4 mv = *(const float4*)(&sMean[r][k]);
            acc[r][0] = fmaf(mv.x, w00, fmaf(mv.y, w10, fmaf(mv.z, w20, fmaf(mv.w, w30, acc[r][0]))));
            acc[r][1] = fmaf(mv.x, w01, fmaf(mv.y, w11, fmaf(mv.z, w21, fmaf(mv.w, w31, acc[r][1]))));
            acc[r][2] = fmaf(mv.x, w02, fmaf(mv.y, w12, fmaf(mv.z, w22, fmaf(mv.w, w32, acc[r][2]))));
        }
    }
    float bb0 = bias[c0], bb1 = bias[c1], bb2 = bias[c2];
    #pragma unroll
    for (int r = 0; r < BM_; r++) {
        float* o = out + (size_t)(m0 + r) * D_;
        if (sAct[r]) {
            o[c0] = tanhf(acc[r][0] + bb0);
            o[c1] = tanhf(acc[r][1] + bb1);
            o[c2] = tanhf(acc[r][2] + bb2);
        } else {
            o[c0] = 0.f; o[c1] = 0.f; o[c2] = 0.f;
        }
    }
}

// Kernel 5: compression_rate scalar.
__global__ void rate_kernel(const float* __restrict__ num, const float* __restrict__ den,
                            float* __restrict__ out) {
    out[0] = num[0] / den[0];
}

extern "C" void kernel_launch(void* const* d_in, const int* in_sizes, int n_in,
                              void* d_out, int out_size, void* d_ws, size_t ws_size,
                              hipStream_t stream) {
    const float* x    = (const float*)d_in[0];
    const int*   seg  = (const int*)d_in[1];
    const int*   padm = (const int*)d_in[2];
    const int*   regm = (const int*)d_in[3];
    const int*   spm  = (const int*)d_in[4];
    const float* Wm   = (const float*)d_in[5];
    const float* bias = (const float*)d_in[6];
    float* out = (float*)d_out;

    char* ws = (char*)d_ws;
    float* num = (float*)ws;
    float* den = num + 1;
    int* keep   = (int*)(ws + 16);
    int* counts = (int*)(ws + 16 + NC_ * 4);
    int* starts = counts + M_;

    float* out_mp = out + (size_t)M_ * D_;   // mask_padding_o   [B_,NC_]
    float* out_mr = out_mp + M_;             // mask_regular_o
    float* out_sp = out_mr + M_;             // mask_seq_pair_o
    float* out_rate = out_sp + M_;           // scalar

    hipMemsetAsync(d_ws, 0, 16, stream);
    meta_kernel<<<M_ / 256, 256, 0, stream>>>(seg, padm, regm, spm, counts, starts,
                                              out_mp, out_mr, out_sp, den);
    keep_kernel<<<NC_ / 256, 256, 0, stream>>>(out_mp, out_mr, out_sp, keep, num);
    mean_kernel<<<M_, 256, 0, stream>>>(x, counts, starts, out);
    gemm_tanh_kernel<<<M_ / BM_, 256, 0, stream>>>(out, Wm, bias, counts, keep);
    rate_kernel<<<1, 1, 0, stream>>>(num, den, out_rate);
}

// Round 2
// 163.043 us; speedup vs baseline: 2.1140x; 2.1140x over previous
//
#include <hip/hip_runtime.h>
#include <math.h>

#define B_   8
#define L_   4096
#define D_   768
#define NC_  4096
#define NCH_ 2048
#define M_   (B_*NC_)    // 32768 full chunk-rows
#define MC_  (B_*NCH_)   // 16384 active compact rows
#define WT_ELEMS (D_*D_)

typedef __attribute__((ext_vector_type(8))) short short8;
typedef __attribute__((ext_vector_type(4))) float f32x4;
typedef unsigned int u32;
typedef unsigned short u16;

// async global->LDS, 16B per lane; dest = wave-uniform base + lane*16
__device__ __forceinline__ void gload16(const void* g, void* l) {
    __builtin_amdgcn_global_load_lds((const __attribute__((address_space(1))) u32*)g,
                                     (__attribute__((address_space(3))) u32*)l, 16, 0, 0);
}

__device__ __forceinline__ u16 f2bf(float f) {           // round-to-nearest-even bf16
    union { float f; u32 u; } v; v.f = f;
    u32 r = v.u + 0x7fffu + ((v.u >> 16) & 1u);
    return (u16)(r >> 16);
}
__device__ __forceinline__ float bf2f(u16 h) {
    union { u32 u; float f; } v; v.u = ((u32)h) << 16;
    return v.f;
}

// A-plane storage lives in d_out's dead rows (c>=2048): 8 spans of 4096
// pseudo-rows x 1536B. plane p, compact row mc -> byte offset in d_out.
__device__ __forceinline__ size_t aplane_byte(int plane, int mc) {
    int q = plane * MC_ + mc;            // 0..32767
    int span = q >> 12;
    int rem  = q & 4095;
    return (size_t)(span * 4096 + 2048) * 3072 + (size_t)rem * 1536;
}

__device__ __forceinline__ int lower_bound(const int* __restrict__ a, int lo, int hi, int v) {
    while (lo < hi) {
        int mid = (lo + hi) >> 1;
        if (a[mid] < v) lo = mid + 1; else hi = mid;
    }
    return lo;
}

// -------- kernel 1: chunk metadata + raw masks + denominator --------
__global__ void meta_kernel(const int* __restrict__ seg,
                            const int* __restrict__ padm,
                            const int* __restrict__ regm,
                            const int* __restrict__ spm,
                            int* __restrict__ counts, int* __restrict__ starts,
                            float* __restrict__ out_mp, float* __restrict__ out_mr,
                            float* __restrict__ out_sp, float* __restrict__ den) {
    int idx = blockIdx.x * blockDim.x + threadIdx.x;   // [0, M_)
    int b = idx >> 12;
    int c = idx & (NC_ - 1);
    const int* row = seg + b * L_;
    int s = lower_bound(row, 0, L_, c);
    int e = lower_bound(row, s, L_, c + 1);
    int cnt = e - s;
    counts[idx] = cnt;
    starts[idx] = s;
    int mp = 0, mr = 0;
    if (cnt > 0) { mp = padm[b * L_ + s]; mr = regm[b * L_ + s]; }
    int sp = (mp == 0) ? -1 : spm[b * L_ + s];
    out_mp[idx] = (float)mp;
    out_mr[idx] = (float)mr;
    out_sp[idx] = (float)sp;
    float dcon = (float)(cnt * mr);
    #pragma unroll
    for (int off = 32; off; off >>= 1) dcon += __shfl_down(dcon, off);
    if ((threadIdx.x & 63) == 0) atomicAdd(den, dcon);
}

// -------- kernel 2: keep[c], masked masks, numerator, act[] --------
__global__ void keep_kernel(float* __restrict__ out_mp, float* __restrict__ out_mr,
                            float* __restrict__ out_sp, const int* __restrict__ counts,
                            int* __restrict__ keep, int* __restrict__ act,
                            float* __restrict__ num) {
    int c = blockIdx.x * blockDim.x + threadIdx.x;   // [0, NC_)
    int k = 0;
    #pragma unroll
    for (int b = 0; b < B_; b++) if (out_mp[b * NC_ + c] > 0.5f) k = 1;
    keep[c] = k;
    float nm = 0.f;
    if (!k) {
        #pragma unroll
        for (int b = 0; b < B_; b++) {
            out_mp[b * NC_ + c] = 0.f;
            out_mr[b * NC_ + c] = 0.f;
            out_sp[b * NC_ + c] = 0.f;
        }
    } else {
        #pragma unroll
        for (int b = 0; b < B_; b++) nm += out_mr[b * NC_ + c];
    }
    if (c < NCH_) {
        #pragma unroll
        for (int b = 0; b < B_; b++)
            act[b * NCH_ + c] = (k && counts[b * NC_ + c] > 0) ? 1 : 0;
    }
    #pragma unroll
    for (int off = 32; off; off >>= 1) nm += __shfl_down(nm, off);
    if ((threadIdx.x & 63) == 0) atomicAdd(num, nm);
}

// -------- kernel 3: W -> transposed bf16 split planes Wt[p][n][k] --------
__global__ void wprep_kernel(const float* __restrict__ Wm, u16* __restrict__ wt) {
    int id = blockIdx.x * 256 + threadIdx.x;   // 0..WT_ELEMS-1
    int n = id / D_, k = id - n * D_;
    float v = Wm[(size_t)k * D_ + n];
    u16 hi = f2bf(v);
    wt[id] = hi;
    wt[WT_ELEMS + id] = f2bf(v - bf2f(hi));
}

// -------- kernel 4: per-chunk fp32 mean -> bf16 hi/lo planes in d_out --------
__global__ void mean_kernel(const float* __restrict__ x,
                            const int* __restrict__ counts,
                            const int* __restrict__ starts,
                            char* __restrict__ outb) {
    int mc = blockIdx.x;                 // [0, MC_)
    int b = mc >> 11, c = mc & (NCH_ - 1);
    int idx = b * NC_ + c;
    int cnt = counts[idx], s = starts[idx];
    int t = threadIdx.x;
    float a0 = 0.f, a1 = 0.f, a2 = 0.f;
    if (cnt > 0) {
        const float* base = x + ((size_t)b * L_ + s) * D_;
        for (int tk = 0; tk < cnt; ++tk) {
            const float* p = base + (size_t)tk * D_;
            a0 += p[t]; a1 += p[t + 256]; a2 += p[t + 512];
        }
        float inv = 1.f / (float)cnt;
        a0 *= inv; a1 *= inv; a2 *= inv;
    }
    u16* hi = (u16*)(outb + aplane_byte(0, mc));
    u16* lo = (u16*)(outb + aplane_byte(1, mc));
    u16 h0 = f2bf(a0), h1 = f2bf(a1), h2 = f2bf(a2);
    hi[t] = h0; hi[t + 256] = h1; hi[t + 512] = h2;
    lo[t] = f2bf(a0 - bf2f(h0));
    lo[t + 256] = f2bf(a1 - bf2f(h1));
    lo[t + 512] = f2bf(a2 - bf2f(h2));
}

// -------- kernel 5: MFMA GEMM, 128x128 tile, BK=32, 3 bf16 planes --------
// C = Ahi*Whi + Ahi*Wlo + Alo*Whi, fp32 accum; epilogue bias+tanh+act mask.
__global__ __launch_bounds__(256) void mfma_gemm_kernel(
        const char* __restrict__ aBytes,          // d_out bytes (A planes)
        const u16* __restrict__ wt,               // [2][D_][D_] transposed planes
        const float* __restrict__ bias,
        const int* __restrict__ act,
        float* __restrict__ out) {
    __shared__ char sA[8192];                     // [128 rows][64 B], XOR-swizzled
    __shared__ char sB[8192];
    int bid = blockIdx.x;
    int wg = (bid & 7) * 96 + (bid >> 3);         // XCD-chunked (768 = 8*96)
    int mtile = wg / 6, ntile = wg - mtile * 6;
    int m0 = mtile << 7, n0 = ntile << 7;
    int t = threadIdx.x;
    int lane = t & 63, w = t >> 6;
    int wm = w >> 1, wn = w & 1;

    // staging: dest linear o=i*16; source uses inverse swizzle so that
    // LDS[o] = element(F(o)), F(o) = o ^ ((((o>>6)^(o>>8))&3)<<4)
    int i0 = t, i1 = t + 256;
    int r0 = i0 >> 2, r1 = i1 >> 2;
    int so0 = r0 * 1536 + (((i0 & 3) ^ ((r0 ^ (r0 >> 2)) & 3)) << 4);
    int so1 = r1 * 1536 + (((i1 & 3) ^ ((r1 ^ (r1 >> 2)) & 3)) << 4);
    char* dA0 = sA + w * 1024;
    char* dA1 = sA + 4096 + w * 1024;
    char* dB0 = sB + w * 1024;
    char* dB1 = sB + 4096 + w * 1024;

    // fragment read addresses (loop-invariant), swizzled
    int aoff[4], boff[4];
    #pragma unroll
    for (int f = 0; f < 4; ++f) {
        int ra = wm * 64 + f * 16 + (lane & 15);
        aoff[f] = ra * 64 + (((lane >> 4) ^ ((ra ^ (ra >> 2)) & 3)) << 4);
        int rb = wn * 64 + f * 16 + (lane & 15);
        boff[f] = rb * 64 + (((lane >> 4) ^ ((rb ^ (rb >> 2)) & 3)) << 4);
    }

    f32x4 acc[4][4] = {};

    #pragma unroll 1
    for (int T = 0; T < 3; ++T) {
        // T0: Ahi*Whi, T1: Ahi*Wlo, T2: Alo*Whi  (A-hi phases adjacent for L2)
        const char* ab = aBytes + aplane_byte((T == 2) ? 1 : 0, m0);
        const char* bb = (const char*)(wt + (size_t)((T == 1) ? 1 : 0) * WT_ELEMS
                                          + (size_t)n0 * D_);
        #pragma unroll 1
        for (int kk = 0; kk < 24; ++kk) {
            int kof = kk << 6;
            __syncthreads();                       // LDS free of prior readers
            gload16(ab + so0 + kof, dA0);
            gload16(ab + so1 + kof, dA1);
            gload16(bb + so0 + kof, dB0);
            gload16(bb + so1 + kof, dB1);
            __syncthreads();                       // drains vmcnt
            short8 af[4], bfr[4];
            #pragma unroll
            for (int f = 0; f < 4; ++f) af[f] = *(const short8*)(sA + aoff[f]);
            #pragma unroll
            for (int f = 0; f < 4; ++f) bfr[f] = *(const short8*)(sB + boff[f]);
            #pragma unroll
            for (int fm = 0; fm < 4; ++fm)
                #pragma unroll
                for (int fn = 0; fn < 4; ++fn)
                    acc[fm][fn] = __builtin_amdgcn_mfma_f32_16x16x32_bf16(
                        af[fm], bfr[fn], acc[fm][fn], 0, 0, 0);
        }
    }

    // epilogue: C/D lane map col=lane&15, row=(lane>>4)*4+reg [m89-verified]
    int ncol[4]; float bs[4];
    #pragma unroll
    for (int fn = 0; fn < 4; ++fn) {
        ncol[fn] = n0 + wn * 64 + fn * 16 + (lane & 15);
        bs[fn] = bias[ncol[fn]];
    }
    #pragma unroll
    for (int fm = 0; fm < 4; ++fm) {
        int rbase = m0 + wm * 64 + fm * 16 + ((lane >> 4) << 2);
        #pragma unroll
        for (int q = 0; q < 4; ++q) {
            int mc = rbase + q;
            int av = act[mc];
            int gr = mc + ((mc >> 11) << 11);      // b*4096 + c
            size_t orow = (size_t)gr * D_;
            #pragma unroll
            for (int fn = 0; fn < 4; ++fn) {
                float v = av ? tanhf(acc[fm][fn][q] + bs[fn]) : 0.f;
                out[orow + ncol[fn]] = v;
            }
        }
    }
}

// -------- kernel 6: zero-fill dead rows (c>=2048) AFTER gemm --------
__global__ void zfill_kernel(float* __restrict__ out) {
    int j = blockIdx.x * 256 + threadIdx.x;        // float4 index, 3145728 total
    size_t jj = (size_t)j << 2;
    int span = (int)(jj / 1572864);                // floats per span = 2048*768
    size_t rem = jj - (size_t)span * 1572864;
    float4* p = (float4*)(out + (size_t)(span * 4096 + 2048) * D_ + rem);
    *p = make_float4(0.f, 0.f, 0.f, 0.f);
}

__global__ void rate_kernel(const float* __restrict__ num, const float* __restrict__ den,
                            float* __restrict__ out) {
    out[0] = num[0] / den[0];
}

extern "C" void kernel_launch(void* const* d_in, const int* in_sizes, int n_in,
                              void* d_out, int out_size, void* d_ws, size_t ws_size,
                              hipStream_t stream) {
    const float* x    = (const float*)d_in[0];
    const int*   seg  = (const int*)d_in[1];
    const int*   padm = (const int*)d_in[2];
    const int*   regm = (const int*)d_in[3];
    const int*   spm  = (const int*)d_in[4];
    const float* Wm   = (const float*)d_in[5];
    const float* bias = (const float*)d_in[6];
    float* out = (float*)d_out;

    char* ws = (char*)d_ws;
    float* num = (float*)ws;
    float* den = num + 1;
    int* keep   = (int*)(ws + 16);
    int* counts = (int*)(ws + 16 + NC_ * 4);
    int* starts = counts + M_;
    int* act    = starts + M_;
    u16* wt     = (u16*)(act + MC_);              // 2*WT_ELEMS u16, 16B-aligned

    float* out_mp = out + (size_t)M_ * D_;
    float* out_mr = out_mp + M_;
    float* out_sp = out_mr + M_;
    float* out_rate = out_sp + M_;

    hipMemsetAsync(d_ws, 0, 16, stream);
    meta_kernel<<<M_ / 256, 256, 0, stream>>>(seg, padm, regm, spm, counts, starts,
                                              out_mp, out_mr, out_sp, den);
    keep_kernel<<<NC_ / 256, 256, 0, stream>>>(out_mp, out_mr, out_sp, counts,
                                               keep, act, num);
    wprep_kernel<<<WT_ELEMS / 256, 256, 0, stream>>>(Wm, wt);
    mean_kernel<<<MC_, 256, 0, stream>>>(x, counts, starts, (char*)d_out);
    mfma_gemm_kernel<<<768, 256, 0, stream>>>((const char*)d_out, wt, bias, act, out);
    zfill_kernel<<<12288, 256, 0, stream>>>(out);
    rate_kernel<<<1, 1, 0, stream>>>(num, den, out_rate);
}

// Round 3
// 133.795 us; speedup vs baseline: 2.5762x; 1.2186x over previous
//
#include <hip/hip_runtime.h>
#include <math.h>

#define B_   8
#define L_   4096
#define D_   768
#define NC_  4096
#define NCH_ 2048
#define M_   (B_*NC_)    // 32768 full chunk-rows
#define MC_  (B_*NCH_)   // 16384 active compact rows
#define WT_ELEMS (D_*D_)
#define NK_  48          // K-steps: 2 planes x 24 (BK=32)

typedef __attribute__((ext_vector_type(8))) short short8;
typedef __attribute__((ext_vector_type(4))) float f32x4;
typedef unsigned int u32;
typedef unsigned short u16;

__device__ __forceinline__ void gload16(const void* g, void* l) {
    __builtin_amdgcn_global_load_lds((const __attribute__((address_space(1))) u32*)g,
                                     (__attribute__((address_space(3))) u32*)l, 16, 0, 0);
}

__device__ __forceinline__ u16 f2bf(float f) {           // RNE bf16
    union { float f; u32 u; } v; v.f = f;
    u32 r = v.u + 0x7fffu + ((v.u >> 16) & 1u);
    return (u16)(r >> 16);
}
__device__ __forceinline__ float bf2f(u16 h) {
    union { u32 u; float f; } v; v.u = ((u32)h) << 16;
    return v.f;
}

// A-plane (bf16 hi of mean) lives in d_out's dead rows (c>=2048), spans 0..3.
__device__ __forceinline__ size_t aplane_byte(int mc) {
    int span = mc >> 12;
    int rem  = mc & 4095;
    return (size_t)(span * 4096 + 2048) * 3072 + (size_t)rem * 1536;
}

__device__ __forceinline__ int lower_bound(const int* __restrict__ a, int lo, int hi, int v) {
    while (lo < hi) {
        int mid = (lo + hi) >> 1;
        if (a[mid] < v) lo = mid + 1; else hi = mid;
    }
    return lo;
}

// -------- kernel 1: chunk metadata + raw masks + denominator --------
__global__ void meta_kernel(const int* __restrict__ seg,
                            const int* __restrict__ padm,
                            const int* __restrict__ regm,
                            const int* __restrict__ spm,
                            int* __restrict__ counts, int* __restrict__ starts,
                            float* __restrict__ out_mp, float* __restrict__ out_mr,
                            float* __restrict__ out_sp, float* __restrict__ den) {
    int idx = blockIdx.x * blockDim.x + threadIdx.x;   // [0, M_)
    int b = idx >> 12;
    int c = idx & (NC_ - 1);
    const int* row = seg + b * L_;
    int s = lower_bound(row, 0, L_, c);
    int e = lower_bound(row, s, L_, c + 1);
    int cnt = e - s;
    counts[idx] = cnt;
    starts[idx] = s;
    int mp = 0, mr = 0;
    if (cnt > 0) { mp = padm[b * L_ + s]; mr = regm[b * L_ + s]; }
    int sp = (mp == 0) ? -1 : spm[b * L_ + s];
    out_mp[idx] = (float)mp;
    out_mr[idx] = (float)mr;
    out_sp[idx] = (float)sp;
    float dcon = (float)(cnt * mr);
    #pragma unroll
    for (int off = 32; off; off >>= 1) dcon += __shfl_down(dcon, off);
    if ((threadIdx.x & 63) == 0) atomicAdd(den, dcon);
}

// -------- kernel 2: keep[c], masked masks, numerator, act[] --------
__global__ void keep_kernel(float* __restrict__ out_mp, float* __restrict__ out_mr,
                            float* __restrict__ out_sp, const int* __restrict__ counts,
                            int* __restrict__ keep, int* __restrict__ act,
                            float* __restrict__ num) {
    int c = blockIdx.x * blockDim.x + threadIdx.x;   // [0, NC_)
    int k = 0;
    #pragma unroll
    for (int b = 0; b < B_; b++) if (out_mp[b * NC_ + c] > 0.5f) k = 1;
    keep[c] = k;
    float nm = 0.f;
    if (!k) {
        #pragma unroll
        for (int b = 0; b < B_; b++) {
            out_mp[b * NC_ + c] = 0.f;
            out_mr[b * NC_ + c] = 0.f;
            out_sp[b * NC_ + c] = 0.f;
        }
    } else {
        #pragma unroll
        for (int b = 0; b < B_; b++) nm += out_mr[b * NC_ + c];
    }
    if (c < NCH_) {
        #pragma unroll
        for (int b = 0; b < B_; b++)
            act[b * NCH_ + c] = (k && counts[b * NC_ + c] > 0) ? 1 : 0;
    }
    #pragma unroll
    for (int off = 32; off; off >>= 1) nm += __shfl_down(nm, off);
    if ((threadIdx.x & 63) == 0) atomicAdd(num, nm);
}

// -------- kernel 3: W -> transposed stacked bf16 planes wt2[n][1536] --------
// k<768: hi(W[k][n]);  k>=768: lo = W - hi
__global__ void wprep_kernel(const float* __restrict__ Wm, u16* __restrict__ wt2) {
    int id = blockIdx.x * 256 + threadIdx.x;   // 0..WT_ELEMS-1
    int n = id / D_, k = id - n * D_;
    float v = Wm[(size_t)k * D_ + n];
    u16 hi = f2bf(v);
    wt2[(size_t)n * 1536 + k] = hi;
    wt2[(size_t)n * 1536 + D_ + k] = f2bf(v - bf2f(hi));
}

// -------- kernel 4: per-chunk fp32 mean -> bf16 hi plane in d_out --------
__global__ void mean_kernel(const float* __restrict__ x,
                            const int* __restrict__ counts,
                            const int* __restrict__ starts,
                            char* __restrict__ outb) {
    int mc = blockIdx.x;                 // [0, MC_)
    int b = mc >> 11, c = mc & (NCH_ - 1);
    int idx = b * NC_ + c;
    int cnt = counts[idx], s = starts[idx];
    int t = threadIdx.x;
    float a0 = 0.f, a1 = 0.f, a2 = 0.f;
    if (cnt > 0) {
        const float* base = x + ((size_t)b * L_ + s) * D_;
        for (int tk = 0; tk < cnt; ++tk) {
            const float* p = base + (size_t)tk * D_;
            a0 += p[t]; a1 += p[t + 256]; a2 += p[t + 512];
        }
        float inv = 1.f / (float)cnt;
        a0 *= inv; a1 *= inv; a2 *= inv;
    }
    u16* hi = (u16*)(outb + aplane_byte(mc));
    hi[t] = f2bf(a0); hi[t + 256] = f2bf(a1); hi[t + 512] = f2bf(a2);
}

// -------- kernel 5: MFMA GEMM, 128x128 tile, BK=32, K=1536 (hi|lo W) --------
// C = Ahi @ [Whi;Wlo stacked], double-buffered 2-phase pipeline.
__global__ __launch_bounds__(256) void mfma_gemm_kernel(
        const char* __restrict__ aBytes,          // d_out bytes (A plane)
        const u16* __restrict__ wt2,              // [768][1536]
        const float* __restrict__ bias,
        const int* __restrict__ act,
        float* __restrict__ out) {
    __shared__ char sA[2][8192];                  // [128 rows][64 B], XOR-swizzled
    __shared__ char sB[2][8192];
    int bid = blockIdx.x;
    int wg = (bid & 7) * 96 + (bid >> 3);         // XCD-chunked (768 = 8*96)
    int mtile = wg / 6, ntile = wg - mtile * 6;
    int m0 = mtile << 7, n0 = ntile << 7;
    int t = threadIdx.x;
    int lane = t & 63, w = t >> 6;
    int wm = w >> 1, wn = w & 1;

    // staging: dest linear chunk i -> LDS[i*16]; source pre-swizzled so that
    // LDS row r, slot s holds source bytes (r, (s ^ swz(r))<<4)
    int i0 = t, i1 = t + 256;
    int r0 = i0 >> 2, r1 = i1 >> 2;
    int sw0 = ((i0 & 3) ^ ((r0 ^ (r0 >> 2)) & 3)) << 4;
    int sw1 = ((i1 & 3) ^ ((r1 ^ (r1 >> 2)) & 3)) << 4;
    const char* aT = aBytes + aplane_byte(m0);               // row stride 1536 B
    const char* bT = (const char*)(wt2 + (size_t)n0 * 1536); // row stride 3072 B
    int soA0 = r0 * 1536 + sw0, soA1 = r1 * 1536 + sw1;
    int soB0 = r0 * 3072 + sw0, soB1 = r1 * 3072 + sw1;
    int dst0 = w * 1024, dst1 = 4096 + w * 1024;

    // fragment read addresses (swizzled, loop-invariant)
    int aoff[4], boff[4];
    #pragma unroll
    for (int f = 0; f < 4; ++f) {
        int ra = wm * 64 + f * 16 + (lane & 15);
        aoff[f] = ra * 64 + (((lane >> 4) ^ ((ra ^ (ra >> 2)) & 3)) << 4);
        int rb = wn * 64 + f * 16 + (lane & 15);
        boff[f] = rb * 64 + (((lane >> 4) ^ ((rb ^ (rb >> 2)) & 3)) << 4);
    }

    f32x4 acc[4][4] = {};

    // prologue: stage kk=0 into buf 0
    gload16(aT + soA0, sA[0] + dst0);
    gload16(aT + soA1, sA[0] + dst1);
    gload16(bT + soB0, sB[0] + dst0);
    gload16(bT + soB1, sB[0] + dst1);
    __syncthreads();

    #pragma unroll 1
    for (int kk = 0; kk < NK_; ++kk) {
        int cur = kk & 1;
        if (kk + 1 < NK_) {
            int nxt = cur ^ 1;
            int kn = kk + 1;
            int akof = (kn >= 24 ? kn - 24 : kn) << 6;   // A wraps (read twice)
            int bkof = kn << 6;
            gload16(aT + soA0 + akof, sA[nxt] + dst0);
            gload16(aT + soA1 + akof, sA[nxt] + dst1);
            gload16(bT + soB0 + bkof, sB[nxt] + dst0);
            gload16(bT + soB1 + bkof, sB[nxt] + dst1);
        }
        short8 af[4], bfr[4];
        #pragma unroll
        for (int f = 0; f < 4; ++f) af[f] = *(const short8*)(sA[cur] + aoff[f]);
        #pragma unroll
        for (int f = 0; f < 4; ++f) bfr[f] = *(const short8*)(sB[cur] + boff[f]);
        #pragma unroll
        for (int fm = 0; fm < 4; ++fm)
            #pragma unroll
            for (int fn = 0; fn < 4; ++fn)
                acc[fm][fn] = __builtin_amdgcn_mfma_f32_16x16x32_bf16(
                    af[fm], bfr[fn], acc[fm][fn], 0, 0, 0);
        __syncthreads();   // compiler emits vmcnt(0) lgkmcnt(0) drain + barrier
    }

    // epilogue: C/D lane map col=lane&15, row=(lane>>4)*4+reg
    int ncol[4]; float bs[4];
    #pragma unroll
    for (int fn = 0; fn < 4; ++fn) {
        ncol[fn] = n0 + wn * 64 + fn * 16 + (lane & 15);
        bs[fn] = bias[ncol[fn]];
    }
    #pragma unroll
    for (int fm = 0; fm < 4; ++fm) {
        int rbase = m0 + wm * 64 + fm * 16 + ((lane >> 4) << 2);
        #pragma unroll
        for (int q = 0; q < 4; ++q) {
            int mc = rbase + q;
            int av = act[mc];
            int gr = mc + ((mc >> 11) << 11);      // b*4096 + c
            size_t orow = (size_t)gr * D_;
            #pragma unroll
            for (int fn = 0; fn < 4; ++fn) {
                float v = av ? tanhf(acc[fm][fn][q] + bs[fn]) : 0.f;
                out[orow + ncol[fn]] = v;
            }
        }
    }
}

// -------- kernel 6: zero-fill dead rows (c>=2048) AFTER gemm --------
__global__ void zfill_kernel(float* __restrict__ out) {
    int j = blockIdx.x * 256 + threadIdx.x;        // float4 index, 3145728 total
    size_t jj = (size_t)j << 2;
    int span = (int)(jj / 1572864);                // floats per span = 2048*768
    size_t rem = jj - (size_t)span * 1572864;
    float4* p = (float4*)(out + (size_t)(span * 4096 + 2048) * D_ + rem);
    *p = make_float4(0.f, 0.f, 0.f, 0.f);
}

__global__ void rate_kernel(const float* __restrict__ num, const float* __restrict__ den,
                            float* __restrict__ out) {
    out[0] = num[0] / den[0];
}

extern "C" void kernel_launch(void* const* d_in, const int* in_sizes, int n_in,
                              void* d_out, int out_size, void* d_ws, size_t ws_size,
                              hipStream_t stream) {
    const float* x    = (const float*)d_in[0];
    const int*   seg  = (const int*)d_in[1];
    const int*   padm = (const int*)d_in[2];
    const int*   regm = (const int*)d_in[3];
    const int*   spm  = (const int*)d_in[4];
    const float* Wm   = (const float*)d_in[5];
    const float* bias = (const float*)d_in[6];
    float* out = (float*)d_out;

    char* ws = (char*)d_ws;
    float* num = (float*)ws;
    float* den = num + 1;
    int* keep   = (int*)(ws + 16);
    int* counts = (int*)(ws + 16 + NC_ * 4);
    int* starts = counts + M_;
    int* act    = starts + M_;
    u16* wt2    = (u16*)(act + MC_);              // 768*1536 u16, 16B-aligned

    float* out_mp = out + (size_t)M_ * D_;
    float* out_mr = out_mp + M_;
    float* out_sp = out_mr + M_;
    float* out_rate = out_sp + M_;

    hipMemsetAsync(d_ws, 0, 16, stream);
    meta_kernel<<<M_ / 256, 256, 0, stream>>>(seg, padm, regm, spm, counts, starts,
                                              out_mp, out_mr, out_sp, den);
    keep_kernel<<<NC_ / 256, 256, 0, stream>>>(out_mp, out_mr, out_sp, counts,
                                               keep, act, num);
    wprep_kernel<<<WT_ELEMS / 256, 256, 0, stream>>>(Wm, wt2);
    mean_kernel<<<MC_, 256, 0, stream>>>(x, counts, starts, (char*)d_out);
    mfma_gemm_kernel<<<768, 256, 0, stream>>>((const char*)d_out, wt2, bias, act, out);
    zfill_kernel<<<12288, 256, 0, stream>>>(out);
    rate_kernel<<<1, 1, 0, stream>>>(num, den, out_rate);
}

// Round 4
// 109.430 us; speedup vs baseline: 3.1498x; 1.2227x over previous
//
#include <hip/hip_runtime.h>
#include <math.h>

#define B_   8
#define L_   4096
#define D_   768
#define NC_  4096
#define NCH_ 2048
#define M_   (B_*NC_)    // 32768 full chunk-rows
#define MC_  (B_*NCH_)   // 16384 active compact rows
#define WT_ELEMS (D_*D_)
#define NK_  24          // K-steps: K=768, BK=32

typedef __attribute__((ext_vector_type(8))) short short8;
typedef __attribute__((ext_vector_type(4))) float f32x4;
typedef unsigned int u32;
typedef unsigned short u16;

__device__ __forceinline__ void gload16(const void* g, void* l) {
    __builtin_amdgcn_global_load_lds((const __attribute__((address_space(1))) u32*)g,
                                     (__attribute__((address_space(3))) u32*)l, 16, 0, 0);
}

__device__ __forceinline__ u16 f2bf(float f) {           // RNE bf16
    union { float f; u32 u; } v; v.f = f;
    u32 r = v.u + 0x7fffu + ((v.u >> 16) & 1u);
    return (u16)(r >> 16);
}

// A-plane (bf16 of mean) lives in d_out's dead rows (c>=2048), spans 0..3.
__device__ __forceinline__ size_t aplane_byte(int mc) {
    int span = mc >> 12;
    int rem  = mc & 4095;
    return (size_t)(span * 4096 + 2048) * 3072 + (size_t)rem * 1536;
}

__device__ __forceinline__ int lower_bound(const int* __restrict__ a, int lo, int hi, int v) {
    while (lo < hi) {
        int mid = (lo + hi) >> 1;
        if (a[mid] < v) lo = mid + 1; else hi = mid;
    }
    return lo;
}

// -------- kernel 1: chunk metadata + raw masks + denominator --------
__global__ void meta_kernel(const int* __restrict__ seg,
                            const int* __restrict__ padm,
                            const int* __restrict__ regm,
                            const int* __restrict__ spm,
                            int* __restrict__ counts, int* __restrict__ starts,
                            float* __restrict__ out_mp, float* __restrict__ out_mr,
                            float* __restrict__ out_sp, float* __restrict__ den) {
    int idx = blockIdx.x * blockDim.x + threadIdx.x;   // [0, M_)
    int b = idx >> 12;
    int c = idx & (NC_ - 1);
    const int* row = seg + b * L_;
    int s = lower_bound(row, 0, L_, c);
    int e = lower_bound(row, s, L_, c + 1);
    int cnt = e - s;
    counts[idx] = cnt;
    starts[idx] = s;
    int mp = 0, mr = 0;
    if (cnt > 0) { mp = padm[b * L_ + s]; mr = regm[b * L_ + s]; }
    int sp = (mp == 0) ? -1 : spm[b * L_ + s];
    out_mp[idx] = (float)mp;
    out_mr[idx] = (float)mr;
    out_sp[idx] = (float)sp;
    float dcon = (float)(cnt * mr);
    #pragma unroll
    for (int off = 32; off; off >>= 1) dcon += __shfl_down(dcon, off);
    if ((threadIdx.x & 63) == 0) atomicAdd(den, dcon);
}

// -------- kernel 2: keep[c], masked masks, numerator, act[] --------
__global__ void keep_kernel(float* __restrict__ out_mp, float* __restrict__ out_mr,
                            float* __restrict__ out_sp, const int* __restrict__ counts,
                            int* __restrict__ keep, int* __restrict__ act,
                            float* __restrict__ num) {
    int c = blockIdx.x * blockDim.x + threadIdx.x;   // [0, NC_)
    int k = 0;
    #pragma unroll
    for (int b = 0; b < B_; b++) if (out_mp[b * NC_ + c] > 0.5f) k = 1;
    keep[c] = k;
    float nm = 0.f;
    if (!k) {
        #pragma unroll
        for (int b = 0; b < B_; b++) {
            out_mp[b * NC_ + c] = 0.f;
            out_mr[b * NC_ + c] = 0.f;
            out_sp[b * NC_ + c] = 0.f;
        }
    } else {
        #pragma unroll
        for (int b = 0; b < B_; b++) nm += out_mr[b * NC_ + c];
    }
    if (c < NCH_) {
        #pragma unroll
        for (int b = 0; b < B_; b++)
            act[b * NCH_ + c] = (k && counts[b * NC_ + c] > 0) ? 1 : 0;
    }
    #pragma unroll
    for (int off = 32; off; off >>= 1) nm += __shfl_down(nm, off);
    if ((threadIdx.x & 63) == 0) atomicAdd(num, nm);
}

// -------- kernel 3: W -> transposed bf16 plane wt[n][k] --------
__global__ void wprep_kernel(const float* __restrict__ Wm, u16* __restrict__ wt) {
    int id = blockIdx.x * 256 + threadIdx.x;   // 0..WT_ELEMS-1
    int n = id / D_, k = id - n * D_;
    wt[id] = f2bf(Wm[(size_t)k * D_ + n]);
}

// -------- kernel 4: per-chunk fp32 mean -> bf16 plane in d_out --------
// 192 threads/block, float4 loads (16B/lane), ushort4 bf16 stores (8B/lane).
__global__ void mean_kernel(const float* __restrict__ x,
                            const int* __restrict__ counts,
                            const int* __restrict__ starts,
                            char* __restrict__ outb) {
    int mc = blockIdx.x;                 // [0, MC_)
    int b = mc >> 11, c = mc & (NCH_ - 1);
    int idx = b * NC_ + c;
    int cnt = counts[idx], s = starts[idx];
    int t = threadIdx.x;                 // 0..191
    float ax = 0.f, ay = 0.f, az = 0.f, aw = 0.f;
    if (cnt > 0) {
        const float4* base = (const float4*)(x + ((size_t)b * L_ + s) * D_) + t;
        for (int tk = 0; tk < cnt; ++tk) {
            float4 v = base[tk * 192];
            ax += v.x; ay += v.y; az += v.z; aw += v.w;
        }
        float inv = 1.f / (float)cnt;
        ax *= inv; ay *= inv; az *= inv; aw *= inv;
    }
    u16* hi = (u16*)(outb + aplane_byte(mc));
    ushort4 h;
    h.x = f2bf(ax); h.y = f2bf(ay); h.z = f2bf(az); h.w = f2bf(aw);
    *(ushort4*)(hi + 4 * t) = h;
}

// -------- kernel 5: MFMA GEMM, 128x128 tile, BK=32, K=768 --------
// C = Abf16 @ Wbf16, double-buffered 2-phase pipeline; bias+tanh+act epilogue.
__global__ __launch_bounds__(256) void mfma_gemm_kernel(
        const char* __restrict__ aBytes,          // d_out bytes (A plane)
        const u16* __restrict__ wt,               // [768][768] transposed
        const float* __restrict__ bias,
        const int* __restrict__ act,
        float* __restrict__ out) {
    __shared__ char sA[2][8192];                  // [128 rows][64 B], XOR-swizzled
    __shared__ char sB[2][8192];
    int bid = blockIdx.x;
    int wg = (bid & 7) * 96 + (bid >> 3);         // XCD-chunked (768 = 8*96)
    int mtile = wg / 6, ntile = wg - mtile * 6;
    int m0 = mtile << 7, n0 = ntile << 7;
    int t = threadIdx.x;
    int lane = t & 63, w = t >> 6;
    int wm = w >> 1, wn = w & 1;

    // staging: LDS row r slot s holds source chunk (r, s ^ swz(r)); dest linear
    int i0 = t, i1 = t + 256;
    int r0 = i0 >> 2, r1 = i1 >> 2;
    int so0 = r0 * 1536 + ((((i0 & 3) ^ ((r0 ^ (r0 >> 2)) & 3))) << 4);
    int so1 = r1 * 1536 + ((((i1 & 3) ^ ((r1 ^ (r1 >> 2)) & 3))) << 4);
    const char* aT = aBytes + aplane_byte(m0);               // row stride 1536 B
    const char* bT = (const char*)(wt + (size_t)n0 * D_);    // row stride 1536 B
    int dst0 = w * 1024, dst1 = 4096 + w * 1024;

    // fragment read addresses (swizzled, loop-invariant)
    int aoff[4], boff[4];
    #pragma unroll
    for (int f = 0; f < 4; ++f) {
        int ra = wm * 64 + f * 16 + (lane & 15);
        aoff[f] = ra * 64 + (((lane >> 4) ^ ((ra ^ (ra >> 2)) & 3)) << 4);
        int rb = wn * 64 + f * 16 + (lane & 15);
        boff[f] = rb * 64 + (((lane >> 4) ^ ((rb ^ (rb >> 2)) & 3)) << 4);
    }

    f32x4 acc[4][4] = {};

    // prologue: stage kk=0 into buf 0
    gload16(aT + so0, sA[0] + dst0);
    gload16(aT + so1, sA[0] + dst1);
    gload16(bT + so0, sB[0] + dst0);
    gload16(bT + so1, sB[0] + dst1);
    __syncthreads();

    #pragma unroll 1
    for (int kk = 0; kk < NK_; ++kk) {
        int cur = kk & 1;
        if (kk + 1 < NK_) {
            int nxt = cur ^ 1;
            int kof = (kk + 1) << 6;
            gload16(aT + so0 + kof, sA[nxt] + dst0);
            gload16(aT + so1 + kof, sA[nxt] + dst1);
            gload16(bT + so0 + kof, sB[nxt] + dst0);
            gload16(bT + so1 + kof, sB[nxt] + dst1);
        }
        short8 af[4], bfr[4];
        #pragma unroll
        for (int f = 0; f < 4; ++f) af[f] = *(const short8*)(sA[cur] + aoff[f]);
        #pragma unroll
        for (int f = 0; f < 4; ++f) bfr[f] = *(const short8*)(sB[cur] + boff[f]);
        #pragma unroll
        for (int fm = 0; fm < 4; ++fm)
            #pragma unroll
            for (int fn = 0; fn < 4; ++fn)
                acc[fm][fn] = __builtin_amdgcn_mfma_f32_16x16x32_bf16(
                    af[fm], bfr[fn], acc[fm][fn], 0, 0, 0);
        __syncthreads();
    }

    // epilogue: C/D lane map col=lane&15, row=(lane>>4)*4+reg
    int ncol[4]; float bs[4];
    #pragma unroll
    for (int fn = 0; fn < 4; ++fn) {
        ncol[fn] = n0 + wn * 64 + fn * 16 + (lane & 15);
        bs[fn] = bias[ncol[fn]];
    }
    #pragma unroll
    for (int fm = 0; fm < 4; ++fm) {
        int rbase = m0 + wm * 64 + fm * 16 + ((lane >> 4) << 2);
        #pragma unroll
        for (int q = 0; q < 4; ++q) {
            int mc = rbase + q;
            int av = act[mc];
            int gr = mc + ((mc >> 11) << 11);      // b*4096 + c
            size_t orow = (size_t)gr * D_;
            #pragma unroll
            for (int fn = 0; fn < 4; ++fn) {
                float v = av ? tanhf(acc[fm][fn][q] + bs[fn]) : 0.f;
                out[orow + ncol[fn]] = v;
            }
        }
    }
}

// -------- kernel 6: zero-fill dead rows (c>=2048) AFTER gemm --------
__global__ void zfill_kernel(float* __restrict__ out) {
    int j = blockIdx.x * 256 + threadIdx.x;        // float4 index, 3145728 total
    size_t jj = (size_t)j << 2;
    int span = (int)(jj / 1572864);                // floats per span = 2048*768
    size_t rem = jj - (size_t)span * 1572864;
    float4* p = (float4*)(out + (size_t)(span * 4096 + 2048) * D_ + rem);
    *p = make_float4(0.f, 0.f, 0.f, 0.f);
}

__global__ void rate_kernel(const float* __restrict__ num, const float* __restrict__ den,
                            float* __restrict__ out) {
    out[0] = num[0] / den[0];
}

extern "C" void kernel_launch(void* const* d_in, const int* in_sizes, int n_in,
                              void* d_out, int out_size, void* d_ws, size_t ws_size,
                              hipStream_t stream) {
    const float* x    = (const float*)d_in[0];
    const int*   seg  = (const int*)d_in[1];
    const int*   padm = (const int*)d_in[2];
    const int*   regm = (const int*)d_in[3];
    const int*   spm  = (const int*)d_in[4];
    const float* Wm   = (const float*)d_in[5];
    const float* bias = (const float*)d_in[6];
    float* out = (float*)d_out;

    char* ws = (char*)d_ws;
    float* num = (float*)ws;
    float* den = num + 1;
    int* keep   = (int*)(ws + 16);
    int* counts = (int*)(ws + 16 + NC_ * 4);
    int* starts = counts + M_;
    int* act    = starts + M_;
    u16* wt     = (u16*)(act + MC_);              // 768*768 u16, 16B-aligned

    float* out_mp = out + (size_t)M_ * D_;
    float* out_mr = out_mp + M_;
    float* out_sp = out_mr + M_;
    float* out_rate = out_sp + M_;

    hipMemsetAsync(d_ws, 0, 16, stream);
    meta_kernel<<<M_ / 256, 256, 0, stream>>>(seg, padm, regm, spm, counts, starts,
                                              out_mp, out_mr, out_sp, den);
    keep_kernel<<<NC_ / 256, 256, 0, stream>>>(out_mp, out_mr, out_sp, counts,
                                               keep, act, num);
    wprep_kernel<<<WT_ELEMS / 256, 256, 0, stream>>>(Wm, wt);
    mean_kernel<<<MC_, 192, 0, stream>>>(x, counts, starts, (char*)d_out);
    mfma_gemm_kernel<<<768, 256, 0, stream>>>((const char*)d_out, wt, bias, act, out);
    zfill_kernel<<<12288, 256, 0, stream>>>(out);
    rate_kernel<<<1, 1, 0, stream>>>(num, den, out_rate);
}

// Round 5
// 108.583 us; speedup vs baseline: 3.1743x; 1.0078x over previous
//
#include <hip/hip_runtime.h>
#include <math.h>

#define B_   8
#define L_   4096
#define D_   768
#define NC_  4096
#define NCH_ 2048
#define M_   (B_*NC_)    // 32768 full chunk-rows
#define MC_  (B_*NCH_)   // 16384 active compact rows
#define WT_ELEMS (D_*D_)
#define NK_  24          // K-steps: K=768, BK=32
#define NCOMPUTE_ 768    // gemm compute blocks (128 mtiles x 6 ntiles)
#define NZERO_ 192       // zero-role blocks (spans 4..7, 25.2 MB)

typedef __attribute__((ext_vector_type(8))) short short8;
typedef __attribute__((ext_vector_type(4))) float f32x4;
typedef unsigned int u32;
typedef unsigned short u16;

__device__ __forceinline__ void gload16(const void* g, void* l) {
    __builtin_amdgcn_global_load_lds((const __attribute__((address_space(1))) u32*)g,
                                     (__attribute__((address_space(3))) u32*)l, 16, 0, 0);
}

__device__ __forceinline__ u16 f2bf(float f) {           // RNE bf16
    union { float f; u32 u; } v; v.f = f;
    u32 r = v.u + 0x7fffu + ((v.u >> 16) & 1u);
    return (u16)(r >> 16);
}

// tanh(x) = 1 - 2/(e^{2x}+1); e^{2x} = 2^{x*2*log2(e)}. Saturates to +-1.
__device__ __forceinline__ float tanh_fast(float x) {
    float e = __builtin_amdgcn_exp2f(x * 2.885390081777927f);
    return 1.f - 2.f * __builtin_amdgcn_rcpf(e + 1.f);
}

// A-plane (bf16 of mean) lives in d_out's dead rows (c>=2048), spans 0..3.
__device__ __forceinline__ size_t aplane_byte(int mc) {
    int span = mc >> 12;
    int rem  = mc & 4095;
    return (size_t)(span * 4096 + 2048) * 3072 + (size_t)rem * 1536;
}

__device__ __forceinline__ int lower_bound(const int* __restrict__ a, int lo, int hi, int v) {
    while (lo < hi) {
        int mid = (lo + hi) >> 1;
        if (a[mid] < v) lo = mid + 1; else hi = mid;
    }
    return lo;
}

// -------- kernel 1: chunk metadata + raw masks + denominator --------
__global__ void meta_kernel(const int* __restrict__ seg,
                            const int* __restrict__ padm,
                            const int* __restrict__ regm,
                            const int* __restrict__ spm,
                            int* __restrict__ counts, int* __restrict__ starts,
                            float* __restrict__ out_mp, float* __restrict__ out_mr,
                            float* __restrict__ out_sp, float* __restrict__ den) {
    int idx = blockIdx.x * blockDim.x + threadIdx.x;   // [0, M_)
    int b = idx >> 12;
    int c = idx & (NC_ - 1);
    const int* row = seg + b * L_;
    int s = lower_bound(row, 0, L_, c);
    int e = lower_bound(row, s, L_, c + 1);
    int cnt = e - s;
    counts[idx] = cnt;
    starts[idx] = s;
    int mp = 0, mr = 0;
    if (cnt > 0) { mp = padm[b * L_ + s]; mr = regm[b * L_ + s]; }
    int sp = (mp == 0) ? -1 : spm[b * L_ + s];
    out_mp[idx] = (float)mp;
    out_mr[idx] = (float)mr;
    out_sp[idx] = (float)sp;
    float dcon = (float)(cnt * mr);
    #pragma unroll
    for (int off = 32; off; off >>= 1) dcon += __shfl_down(dcon, off);
    if ((threadIdx.x & 63) == 0) atomicAdd(den, dcon);
}

// -------- kernel 2: keep[c], masked masks, numerator, act[] --------
__global__ void keep_kernel(float* __restrict__ out_mp, float* __restrict__ out_mr,
                            float* __restrict__ out_sp, const int* __restrict__ counts,
                            int* __restrict__ keep, int* __restrict__ act,
                            float* __restrict__ num) {
    int c = blockIdx.x * blockDim.x + threadIdx.x;   // [0, NC_)
    int k = 0;
    #pragma unroll
    for (int b = 0; b < B_; b++) if (out_mp[b * NC_ + c] > 0.5f) k = 1;
    keep[c] = k;
    float nm = 0.f;
    if (!k) {
        #pragma unroll
        for (int b = 0; b < B_; b++) {
            out_mp[b * NC_ + c] = 0.f;
            out_mr[b * NC_ + c] = 0.f;
            out_sp[b * NC_ + c] = 0.f;
        }
    } else {
        #pragma unroll
        for (int b = 0; b < B_; b++) nm += out_mr[b * NC_ + c];
    }
    if (c < NCH_) {
        #pragma unroll
        for (int b = 0; b < B_; b++)
            act[b * NCH_ + c] = (k && counts[b * NC_ + c] > 0) ? 1 : 0;
    }
    #pragma unroll
    for (int off = 32; off; off >>= 1) nm += __shfl_down(nm, off);
    if ((threadIdx.x & 63) == 0) atomicAdd(num, nm);
}

// -------- kernel 3: W[k][n] -> wt[n][k] bf16, LDS 64x64 transpose --------
__global__ void wprep_kernel(const float* __restrict__ Wm, u16* __restrict__ wt) {
    __shared__ float tile[64][65];
    int bk = blockIdx.x % 12, bn = blockIdx.x / 12;
    int k0 = bk * 64, n0 = bn * 64;
    int t = threadIdx.x;
    int ln = t & 63, lw = t >> 6;
    #pragma unroll
    for (int p = 0; p < 16; ++p) {
        int kl = lw + p * 4;
        tile[kl][ln] = Wm[(size_t)(k0 + kl) * D_ + n0 + ln];   // coalesced over n
    }
    __syncthreads();
    #pragma unroll
    for (int p = 0; p < 16; ++p) {
        int nl = lw + p * 4;
        wt[(size_t)(n0 + nl) * D_ + k0 + ln] = f2bf(tile[ln][nl]);  // coalesced over k
    }
}

// -------- kernel 4: per-chunk fp32 mean -> bf16 plane in d_out; + rate --------
__global__ void mean_kernel(const float* __restrict__ x,
                            const int* __restrict__ counts,
                            const int* __restrict__ starts,
                            char* __restrict__ outb,
                            const float* __restrict__ num, const float* __restrict__ den,
                            float* __restrict__ rateOut) {
    int mc = blockIdx.x;                 // [0, MC_)
    if (mc == 0 && threadIdx.x == 0) rateOut[0] = num[0] / den[0];  // after keep (stream order)
    int b = mc >> 11, c = mc & (NCH_ - 1);
    int idx = b * NC_ + c;
    int cnt = counts[idx], s = starts[idx];
    int t = threadIdx.x;                 // 0..191
    float ax = 0.f, ay = 0.f, az = 0.f, aw = 0.f;
    if (cnt > 0) {
        const float4* base = (const float4*)(x + ((size_t)b * L_ + s) * D_) + t;
        for (int tk = 0; tk < cnt; ++tk) {
            float4 v = base[tk * 192];
            ax += v.x; ay += v.y; az += v.z; aw += v.w;
        }
        float inv = 1.f / (float)cnt;
        ax *= inv; ay *= inv; az *= inv; aw *= inv;
    }
    u16* hi = (u16*)(outb + aplane_byte(mc));
    ushort4 h;
    h.x = f2bf(ax); h.y = f2bf(ay); h.z = f2bf(az); h.w = f2bf(aw);
    *(ushort4*)(hi + 4 * t) = h;
}

// -------- kernel 5: MFMA GEMM (blocks 0..767) + dead-region zeroing --------
// Compute: C = Abf16 @ Wbf16, 128x128 tile, BK=32, 2-phase dbuf; epilogue
// bias + tanh_fast + act mask. Last finisher per mtile (atomic) zeroes its
// A-plane region (spans 0..3). Blocks 768..959 zero spans 4..7.
__global__ __launch_bounds__(256) void mfma_gemm_kernel(
        const char* __restrict__ aBytes,          // d_out bytes (A plane)
        const u16* __restrict__ wt,               // [768][768] transposed
        const float* __restrict__ bias,
        const int* __restrict__ act,
        int* __restrict__ cnt128,                 // [128] zeroed each launch
        float* __restrict__ out) {
    int bid = blockIdx.x;
    int t = threadIdx.x;
    if (bid >= NCOMPUTE_) {
        // zero-role: spans 4..7, 192 blocks x 131072 B
        int j = bid - NCOMPUTE_;
        int s = j / 48;
        size_t base = (size_t)((4 + s) * 4096 + 2048) * 3072 + (size_t)(j % 48) * 131072;
        float4* p = (float4*)((char*)out + base);
        float4 z = make_float4(0.f, 0.f, 0.f, 0.f);
        #pragma unroll
        for (int i = 0; i < 32; ++i) p[t + i * 256] = z;
        return;
    }
    __shared__ char sA[2][8192];                  // [128 rows][64 B], XOR-swizzled
    __shared__ char sB[2][8192];
    __shared__ int sLast;
    int wg = (bid & 7) * 96 + (bid >> 3);         // XCD-chunked (768 = 8*96)
    int mtile = wg / 6, ntile = wg - mtile * 6;
    int m0 = mtile << 7, n0 = ntile << 7;
    int lane = t & 63, w = t >> 6;
    int wm = w >> 1, wn = w & 1;

    int i0 = t, i1 = t + 256;
    int r0 = i0 >> 2, r1 = i1 >> 2;
    int so0 = r0 * 1536 + ((((i0 & 3) ^ ((r0 ^ (r0 >> 2)) & 3))) << 4);
    int so1 = r1 * 1536 + ((((i1 & 3) ^ ((r1 ^ (r1 >> 2)) & 3))) << 4);
    const char* aT = aBytes + aplane_byte(m0);               // row stride 1536 B
    const char* bT = (const char*)(wt + (size_t)n0 * D_);    // row stride 1536 B
    int dst0 = w * 1024, dst1 = 4096 + w * 1024;

    int aoff[4], boff[4];
    #pragma unroll
    for (int f = 0; f < 4; ++f) {
        int ra = wm * 64 + f * 16 + (lane & 15);
        aoff[f] = ra * 64 + (((lane >> 4) ^ ((ra ^ (ra >> 2)) & 3)) << 4);
        int rb = wn * 64 + f * 16 + (lane & 15);
        boff[f] = rb * 64 + (((lane >> 4) ^ ((rb ^ (rb >> 2)) & 3)) << 4);
    }

    f32x4 acc[4][4] = {};

    gload16(aT + so0, sA[0] + dst0);
    gload16(aT + so1, sA[0] + dst1);
    gload16(bT + so0, sB[0] + dst0);
    gload16(bT + so1, sB[0] + dst1);
    __syncthreads();

    #pragma unroll 1
    for (int kk = 0; kk < NK_; ++kk) {
        int cur = kk & 1;
        if (kk + 1 < NK_) {
            int nxt = cur ^ 1;
            int kof = (kk + 1) << 6;
            gload16(aT + so0 + kof, sA[nxt] + dst0);
            gload16(aT + so1 + kof, sA[nxt] + dst1);
            gload16(bT + so0 + kof, sB[nxt] + dst0);
            gload16(bT + so1 + kof, sB[nxt] + dst1);
        }
        short8 af[4], bfr[4];
        #pragma unroll
        for (int f = 0; f < 4; ++f) af[f] = *(const short8*)(sA[cur] + aoff[f]);
        #pragma unroll
        for (int f = 0; f < 4; ++f) bfr[f] = *(const short8*)(sB[cur] + boff[f]);
        #pragma unroll
        for (int fm = 0; fm < 4; ++fm)
            #pragma unroll
            for (int fn = 0; fn < 4; ++fn)
                acc[fm][fn] = __builtin_amdgcn_mfma_f32_16x16x32_bf16(
                    af[fm], bfr[fn], acc[fm][fn], 0, 0, 0);
        __syncthreads();
    }

    // epilogue: C/D lane map col=lane&15, row=(lane>>4)*4+reg
    int ncol[4]; float bs[4];
    #pragma unroll
    for (int fn = 0; fn < 4; ++fn) {
        ncol[fn] = n0 + wn * 64 + fn * 16 + (lane & 15);
        bs[fn] = bias[ncol[fn]];
    }
    #pragma unroll
    for (int fm = 0; fm < 4; ++fm) {
        int rbase = m0 + wm * 64 + fm * 16 + ((lane >> 4) << 2);
        #pragma unroll
        for (int q = 0; q < 4; ++q) {
            int mc = rbase + q;
            int av = act[mc];
            int gr = mc + ((mc >> 11) << 11);      // b*4096 + c
            size_t orow = (size_t)gr * D_;
            #pragma unroll
            for (int fn = 0; fn < 4; ++fn) {
                float v = av ? tanh_fast(acc[fm][fn][q] + bs[fn]) : 0.f;
                out[orow + ncol[fn]] = v;
            }
        }
    }

    // last block of this mtile (all 6 ntile readers done) zeroes the A region
    if (t == 0) sLast = atomicAdd(&cnt128[mtile], 1);
    __syncthreads();
    if (sLast == 5) {
        float4* p = (float4*)((char*)out + aplane_byte(m0));  // 128*1536 B contiguous
        float4 z = make_float4(0.f, 0.f, 0.f, 0.f);
        #pragma unroll
        for (int i = 0; i < 48; ++i) p[t + i * 256] = z;
    }
}

extern "C" void kernel_launch(void* const* d_in, const int* in_sizes, int n_in,
                              void* d_out, int out_size, void* d_ws, size_t ws_size,
                              hipStream_t stream) {
    const float* x    = (const float*)d_in[0];
    const int*   seg  = (const int*)d_in[1];
    const int*   padm = (const int*)d_in[2];
    const int*   regm = (const int*)d_in[3];
    const int*   spm  = (const int*)d_in[4];
    const float* Wm   = (const float*)d_in[5];
    const float* bias = (const float*)d_in[6];
    float* out = (float*)d_out;

    char* ws = (char*)d_ws;
    float* num = (float*)ws;
    float* den = num + 1;
    int* cnt128 = (int*)(ws + 16);                // [128]
    int* keep   = (int*)(ws + 1024);
    int* counts = (int*)(ws + 1024 + NC_ * 4);
    int* starts = counts + M_;
    int* act    = starts + M_;
    u16* wt     = (u16*)(act + MC_);              // 768*768 u16, 16B-aligned

    float* out_mp = out + (size_t)M_ * D_;
    float* out_mr = out_mp + M_;
    float* out_sp = out_mr + M_;
    float* out_rate = out_sp + M_;

    hipMemsetAsync(d_ws, 0, 1024, stream);        // num/den + cnt128
    meta_kernel<<<M_ / 256, 256, 0, stream>>>(seg, padm, regm, spm, counts, starts,
                                              out_mp, out_mr, out_sp, den);
    keep_kernel<<<NC_ / 256, 256, 0, stream>>>(out_mp, out_mr, out_sp, counts,
                                               keep, act, num);
    wprep_kernel<<<144, 256, 0, stream>>>(Wm, wt);
    mean_kernel<<<MC_, 192, 0, stream>>>(x, counts, starts, (char*)d_out,
                                         num, den, out_rate);
    mfma_gemm_kernel<<<NCOMPUTE_ + NZERO_, 256, 0, stream>>>(
        (const char*)d_out, wt, bias, act, cnt128, out);
}

// Round 6
// 101.030 us; speedup vs baseline: 3.4116x; 1.0748x over previous
//
#include <hip/hip_runtime.h>
#include <math.h>

#define B_   8
#define L_   4096
#define D_   768
#define NC_  4096
#define NCH_ 2048
#define M_   (B_*NC_)    // 32768 full chunk-rows
#define MC_  (B_*NCH_)   // 16384 active compact rows
#define WT_ELEMS (D_*D_)
#define NKT_ 24          // K-tiles of 32 (K=768)
#define GEMM_BLOCKS 192  // 64 mtiles x 3 ntiles (256x256 tiles)
#define MEAN_ZB 512      // zero-role blocks appended to mean grid (spans 4..7)

typedef __attribute__((ext_vector_type(8))) short short8;
typedef __attribute__((ext_vector_type(4))) float f32x4;
typedef unsigned int u32;
typedef unsigned short u16;

__device__ __forceinline__ void gload16(const void* g, void* l) {
    __builtin_amdgcn_global_load_lds((const __attribute__((address_space(1))) u32*)g,
                                     (__attribute__((address_space(3))) u32*)l, 16, 0, 0);
}

__device__ __forceinline__ u16 f2bf(float f) {           // RNE bf16
    union { float f; u32 u; } v; v.f = f;
    u32 r = v.u + 0x7fffu + ((v.u >> 16) & 1u);
    return (u16)(r >> 16);
}

// tanh(x) = 1 - 2/(e^{2x}+1); e^{2x} = 2^{x*2*log2 e}. Saturates to +-1.
__device__ __forceinline__ float tanh_fast(float x) {
    float e = __builtin_amdgcn_exp2f(x * 2.885390081777927f);
    return 1.f - 2.f * __builtin_amdgcn_rcpf(e + 1.f);
}

// A-plane (bf16 of mean) lives in d_out's dead rows (c>=2048), spans 0..3.
// Each span = 2048 dead rows (3072 B) = 4096 pseudo-rows of 1536 B.
__device__ __forceinline__ size_t aplane_byte(int mc) {
    int span = mc >> 12;
    int rem  = mc & 4095;
    return (size_t)(span * 4096 + 2048) * 3072 + (size_t)rem * 1536;
}

__device__ __forceinline__ int lower_bound(const int* __restrict__ a, int lo, int hi, int v) {
    while (lo < hi) {
        int mid = (lo + hi) >> 1;
        if (a[mid] < v) lo = mid + 1; else hi = mid;
    }
    return lo;
}

// -------- kernel 1: chunk metadata + raw masks + denominator --------
__global__ void meta_kernel(const int* __restrict__ seg,
                            const int* __restrict__ padm,
                            const int* __restrict__ regm,
                            const int* __restrict__ spm,
                            int* __restrict__ counts, int* __restrict__ starts,
                            float* __restrict__ out_mp, float* __restrict__ out_mr,
                            float* __restrict__ out_sp, float* __restrict__ den) {
    int idx = blockIdx.x * blockDim.x + threadIdx.x;   // [0, M_)
    int b = idx >> 12;
    int c = idx & (NC_ - 1);
    const int* row = seg + b * L_;
    int s = lower_bound(row, 0, L_, c);
    int e = lower_bound(row, s, L_, c + 1);
    int cnt = e - s;
    counts[idx] = cnt;
    starts[idx] = s;
    int mp = 0, mr = 0;
    if (cnt > 0) { mp = padm[b * L_ + s]; mr = regm[b * L_ + s]; }
    int sp = (mp == 0) ? -1 : spm[b * L_ + s];
    out_mp[idx] = (float)mp;
    out_mr[idx] = (float)mr;
    out_sp[idx] = (float)sp;
    float dcon = (float)(cnt * mr);
    #pragma unroll
    for (int off = 32; off; off >>= 1) dcon += __shfl_down(dcon, off);
    if ((threadIdx.x & 63) == 0) atomicAdd(den, dcon);
}

// -------- kernel 2: keep[c], masked masks, numerator, act[] --------
__global__ void keep_kernel(float* __restrict__ out_mp, float* __restrict__ out_mr,
                            float* __restrict__ out_sp, const int* __restrict__ counts,
                            int* __restrict__ keep, int* __restrict__ act,
                            float* __restrict__ num) {
    int c = blockIdx.x * blockDim.x + threadIdx.x;   // [0, NC_)
    int k = 0;
    #pragma unroll
    for (int b = 0; b < B_; b++) if (out_mp[b * NC_ + c] > 0.5f) k = 1;
    keep[c] = k;
    float nm = 0.f;
    if (!k) {
        #pragma unroll
        for (int b = 0; b < B_; b++) {
            out_mp[b * NC_ + c] = 0.f;
            out_mr[b * NC_ + c] = 0.f;
            out_sp[b * NC_ + c] = 0.f;
        }
    } else {
        #pragma unroll
        for (int b = 0; b < B_; b++) nm += out_mr[b * NC_ + c];
    }
    if (c < NCH_) {
        #pragma unroll
        for (int b = 0; b < B_; b++)
            act[b * NCH_ + c] = (k && counts[b * NC_ + c] > 0) ? 1 : 0;
    }
    #pragma unroll
    for (int off = 32; off; off >>= 1) nm += __shfl_down(nm, off);
    if ((threadIdx.x & 63) == 0) atomicAdd(num, nm);
}

// -------- kernel 3: W[k][n] -> wt[n][k] bf16, LDS 64x64 transpose --------
__global__ void wprep_kernel(const float* __restrict__ Wm, u16* __restrict__ wt) {
    __shared__ float tile[64][65];
    int bk = blockIdx.x % 12, bn = blockIdx.x / 12;
    int k0 = bk * 64, n0 = bn * 64;
    int t = threadIdx.x;
    int ln = t & 63, lw = t >> 6;
    #pragma unroll
    for (int p = 0; p < 16; ++p) {
        int kl = lw + p * 4;
        tile[kl][ln] = Wm[(size_t)(k0 + kl) * D_ + n0 + ln];   // coalesced over n
    }
    __syncthreads();
    #pragma unroll
    for (int p = 0; p < 16; ++p) {
        int nl = lw + p * 4;
        wt[(size_t)(n0 + nl) * D_ + k0 + ln] = f2bf(tile[ln][nl]);  // coalesced over k
    }
}

// -------- kernel 4: per-chunk mean -> bf16 plane; + rate; + zero spans 4-7 ----
__global__ void mean_kernel(const float* __restrict__ x,
                            const int* __restrict__ counts,
                            const int* __restrict__ starts,
                            char* __restrict__ outb,
                            const float* __restrict__ num, const float* __restrict__ den,
                            float* __restrict__ rateOut) {
    int mc = blockIdx.x;
    int t = threadIdx.x;                 // 0..191
    if (mc >= MC_) {                     // zero-role: spans 4..7 (25.2 MB)
        int z = mc - MC_;                // 0..511
        int sp = z >> 7;
        size_t base = (size_t)((4 + sp) * 4096 + 2048) * 3072 + (size_t)(z & 127) * 49152;
        float4* p = (float4*)(outb + base);
        float4 zz = make_float4(0.f, 0.f, 0.f, 0.f);
        #pragma unroll
        for (int i = 0; i < 16; ++i) p[t + i * 192] = zz;
        return;
    }
    if (mc == 0 && t == 0) rateOut[0] = num[0] / den[0];   // stream-ordered after keep
    int b = mc >> 11, c = mc & (NCH_ - 1);
    int idx = b * NC_ + c;
    int cnt = counts[idx], s = starts[idx];
    float ax = 0.f, ay = 0.f, az = 0.f, aw = 0.f;
    if (cnt > 0) {
        const float4* base = (const float4*)(x + ((size_t)b * L_ + s) * D_) + t;
        for (int tk = 0; tk < cnt; ++tk) {
            float4 v = base[tk * 192];
            ax += v.x; ay += v.y; az += v.z; aw += v.w;
        }
        float inv = 1.f / (float)cnt;
        ax *= inv; ay *= inv; az *= inv; aw *= inv;
    }
    u16* hi = (u16*)(outb + aplane_byte(mc));
    ushort4 h;
    h.x = f2bf(ax); h.y = f2bf(ay); h.z = f2bf(az); h.w = f2bf(aw);
    *(ushort4*)(hi + 4 * t) = h;
}

// -------- kernel 5: 256x256 deep-pipelined MFMA GEMM --------
// BK=32, 4 LDS buffers/operand, staging 2 K-tiles ahead -> wait vmcnt(4)
// (counted, never 0 until last iter), one raw s_barrier per K-tile,
// 2 phases x 16 MFMA with setprio. LDS slot-XOR swizzle: physical slot
// p = s ^ ((r ^ (r>>2)) & 3); ds_read (slot = lane>>4 over 16 rows) then
// sweeps each 1KB region bijectively -> conflict-free. Staging pre-applies
// the same involution on the global source (linear LDS dest).
__global__ __launch_bounds__(512, 2) void gemm8_kernel(
        const char* __restrict__ aBytes,          // d_out bytes (A plane)
        const u16* __restrict__ wt,               // [768][768] transposed bf16
        const float* __restrict__ bias,
        const int* __restrict__ act,
        float* __restrict__ out) {
    __shared__ char sA[4 * 16384];                // 64 KB: 4 bufs x 256 rows x 64 B
    __shared__ char sB[4 * 16384];
    int bid = blockIdx.x;
    int wg = (bid & 7) * 24 + (bid >> 3);         // XCD-chunked (192 = 8*24)
    int mtile = wg / 3, ntile = wg - mtile * 3;
    int m0 = mtile << 8, n0 = ntile << 8;
    int t = threadIdx.x;
    int lane = t & 63, w = t >> 6;
    int wm = w >> 2, wn = w & 3;                  // 2x4 wave grid; wave owns 128x64

    const char* aT = aBytes + aplane_byte(m0);               // row stride 1536 B
    const char* bT = (const char*)(wt + (size_t)n0 * D_);    // row stride 1536 B

    // staging source offsets (inverse-swizzled), calls j=0 (rows 0-127), j=1 (128-255)
    int i0 = t, i1 = t + 512;
    int r0 = i0 >> 2, s0 = i0 & 3, r1 = i1 >> 2, s1 = i1 & 3;
    int src0 = r0 * 1536 + ((s0 ^ ((r0 ^ (r0 >> 2)) & 3)) << 4);
    int src1 = r1 * 1536 + ((s1 ^ ((r1 ^ (r1 >> 2)) & 3)) << 4);
    int db0 = w * 1024;                           // wave-uniform LDS dest bases
    int db1 = 8192 + w * 1024;

    // fragment read offsets (swizzled, loop-invariant)
    int aoff[8], boff[4];
    #pragma unroll
    for (int f = 0; f < 8; ++f) {
        int rA = wm * 128 + f * 16 + (lane & 15);
        aoff[f] = rA * 64 + ((((lane >> 4)) ^ ((rA ^ (rA >> 2)) & 3)) << 4);
    }
    #pragma unroll
    for (int g = 0; g < 4; ++g) {
        int rB = wn * 64 + g * 16 + (lane & 15);
        boff[g] = rB * 64 + ((((lane >> 4)) ^ ((rB ^ (rB >> 2)) & 3)) << 4);
    }

    f32x4 acc[8][4] = {};

    // prologue: stage K-tiles 0 and 1 (order matters for vmcnt counting)
    #pragma unroll
    for (int p = 0; p < 2; ++p) {
        int kof = p << 6;
        char* dA = sA + p * 16384;
        char* dB = sB + p * 16384;
        gload16(aT + src0 + kof, dA + db0);
        gload16(aT + src1 + kof, dA + db1);
        gload16(bT + src0 + kof, dB + db0);
        gload16(bT + src1 + kof, dB + db1);
    }

    #pragma unroll 1
    for (int kt = 0; kt < NKT_; ++kt) {
        // tile kt's loads are the oldest; exactly 4 newer (tile kt+1) in flight
        if (kt < NKT_ - 1) asm volatile("s_waitcnt vmcnt(4)" ::: "memory");
        else               asm volatile("s_waitcnt vmcnt(0)" ::: "memory");
        __builtin_amdgcn_s_barrier();             // all waves' tile-kt loads landed
        __builtin_amdgcn_sched_barrier(0);
        const char* curA = sA + (kt & 3) * 16384;
        const char* curB = sB + (kt & 3) * 16384;
        int kn = kt + 2;
        int kof = kn << 6;
        // ---- phase A: frags m0-3 + B, stage next A-tile, 16 MFMA ----
        short8 afr[4], bfr[4];
        #pragma unroll
        for (int f = 0; f < 4; ++f) afr[f] = *(const short8*)(curA + aoff[f]);
        #pragma unroll
        for (int g = 0; g < 4; ++g) bfr[g] = *(const short8*)(curB + boff[g]);
        if (kn < NKT_) {
            char* dA = sA + (kn & 3) * 16384;     // read at iter kt-2: free
            gload16(aT + src0 + kof, dA + db0);
            gload16(aT + src1 + kof, dA + db1);
        }
        __builtin_amdgcn_s_setprio(1);
        #pragma unroll
        for (int f = 0; f < 4; ++f)
            #pragma unroll
            for (int g = 0; g < 4; ++g)
                acc[f][g] = __builtin_amdgcn_mfma_f32_16x16x32_bf16(
                    afr[f], bfr[g], acc[f][g], 0, 0, 0);
        __builtin_amdgcn_s_setprio(0);
        // ---- phase B: frags m4-7, stage next B-tile, 16 MFMA ----
        short8 afr2[4];
        #pragma unroll
        for (int f = 0; f < 4; ++f) afr2[f] = *(const short8*)(curA + aoff[f + 4]);
        if (kn < NKT_) {
            char* dB = sB + (kn & 3) * 16384;
            gload16(bT + src0 + kof, dB + db0);
            gload16(bT + src1 + kof, dB + db1);
        }
        __builtin_amdgcn_s_setprio(1);
        #pragma unroll
        for (int f = 0; f < 4; ++f)
            #pragma unroll
            for (int g = 0; g < 4; ++g)
                acc[f + 4][g] = __builtin_amdgcn_mfma_f32_16x16x32_bf16(
                    afr2[f], bfr[g], acc[f + 4][g], 0, 0, 0);
        __builtin_amdgcn_s_setprio(0);
        __builtin_amdgcn_sched_barrier(0);
    }

    // epilogue: C/D lane map col=lane&15, row=(lane>>4)*4+reg
    int ncol[4]; float bs[4];
    #pragma unroll
    for (int g = 0; g < 4; ++g) {
        ncol[g] = n0 + wn * 64 + g * 16 + (lane & 15);
        bs[g] = bias[ncol[g]];
    }
    #pragma unroll
    for (int f = 0; f < 8; ++f) {
        int rbase = m0 + wm * 128 + f * 16 + ((lane >> 4) << 2);
        #pragma unroll
        for (int q = 0; q < 4; ++q) {
            int mc = rbase + q;
            int av = act[mc];
            int gr = mc + ((mc >> 11) << 11);      // b*4096 + c
            size_t orow = (size_t)gr * D_;
            #pragma unroll
            for (int g = 0; g < 4; ++g) {
                float v = av ? tanh_fast(acc[f][g][q] + bs[g]) : 0.f;
                out[orow + ncol[g]] = v;
            }
        }
    }
}

// -------- kernel 6: zero spans 0-3 (A-plane) AFTER gemm --------
__global__ void zfill0_kernel(char* __restrict__ outb) {
    int z = blockIdx.x;                  // 0..1535
    int sp = z / 384;
    size_t base = (size_t)(sp * 4096 + 2048) * 3072 + (size_t)(z % 384) * 16384;
    float4* p = (float4*)(outb + base);
    float4 zz = make_float4(0.f, 0.f, 0.f, 0.f);
    int t = threadIdx.x;
    #pragma unroll
    for (int i = 0; i < 4; ++i) p[t + i * 256] = zz;
}

extern "C" void kernel_launch(void* const* d_in, const int* in_sizes, int n_in,
                              void* d_out, int out_size, void* d_ws, size_t ws_size,
                              hipStream_t stream) {
    const float* x    = (const float*)d_in[0];
    const int*   seg  = (const int*)d_in[1];
    const int*   padm = (const int*)d_in[2];
    const int*   regm = (const int*)d_in[3];
    const int*   spm  = (const int*)d_in[4];
    const float* Wm   = (const float*)d_in[5];
    const float* bias = (const float*)d_in[6];
    float* out = (float*)d_out;

    char* ws = (char*)d_ws;
    float* num = (float*)ws;
    float* den = num + 1;
    int* keep   = (int*)(ws + 1024);
    int* counts = (int*)(ws + 1024 + NC_ * 4);
    int* starts = counts + M_;
    int* act    = starts + M_;
    u16* wt     = (u16*)(act + MC_);              // 768*768 u16, 16B-aligned

    float* out_mp = out + (size_t)M_ * D_;
    float* out_mr = out_mp + M_;
    float* out_sp = out_mr + M_;
    float* out_rate = out_sp + M_;

    hipMemsetAsync(d_ws, 0, 16, stream);          // num/den
    meta_kernel<<<M_ / 256, 256, 0, stream>>>(seg, padm, regm, spm, counts, starts,
                                              out_mp, out_mr, out_sp, den);
    keep_kernel<<<NC_ / 256, 256, 0, stream>>>(out_mp, out_mr, out_sp, counts,
                                               keep, act, num);
    wprep_kernel<<<144, 256, 0, stream>>>(Wm, wt);
    mean_kernel<<<MC_ + MEAN_ZB, 192, 0, stream>>>(x, counts, starts, (char*)d_out,
                                                   num, den, out_rate);
    gemm8_kernel<<<GEMM_BLOCKS, 512, 0, stream>>>((const char*)d_out, wt, bias, act, out);
    zfill0_kernel<<<1536, 256, 0, stream>>>((char*)d_out);
}

// Round 7
// 81.833 us; speedup vs baseline: 4.2119x; 1.2346x over previous
//
#include <hip/hip_runtime.h>
#include <math.h>

#define B_   8
#define L_   4096
#define D_   768
#define NC_  4096
#define NCH_ 2048
#define M_   (B_*NC_)    // 32768 (b,c) pairs
#define MC_  (B_*NCH_)   // 16384 active compact rows
#define NKT_ 24          // K-tiles of 32 (K=768)
#define META_BLOCKS 128
#define WPREP_BLOCKS 144
#define GEMM_BLOCKS 256  // 128 mtiles (BM=128) x 2 ntiles (BN=384)
#define MEAN_ZB 512      // zero-role blocks in mean grid (spans 4..7)

typedef __attribute__((ext_vector_type(8))) short short8;
typedef __attribute__((ext_vector_type(4))) float f32x4;
typedef unsigned int u32;
typedef unsigned short u16;

__device__ __forceinline__ void gload16(const void* g, void* l) {
    __builtin_amdgcn_global_load_lds((const __attribute__((address_space(1))) u32*)g,
                                     (__attribute__((address_space(3))) u32*)l, 16, 0, 0);
}

__device__ __forceinline__ u16 f2bf(float f) {           // RNE bf16
    union { float f; u32 u; } v; v.f = f;
    u32 r = v.u + 0x7fffu + ((v.u >> 16) & 1u);
    return (u16)(r >> 16);
}

// tanh(x) = 1 - 2/(e^{2x}+1). Saturates to +-1.
__device__ __forceinline__ float tanh_fast(float x) {
    float e = __builtin_amdgcn_exp2f(x * 2.885390081777927f);
    return 1.f - 2.f * __builtin_amdgcn_rcpf(e + 1.f);
}

// A-plane (bf16 of mean) lives in d_out's dead rows (c>=2048), spans 0..3.
__device__ __forceinline__ size_t aplane_byte(int mc) {
    int span = mc >> 12;
    int rem  = mc & 4095;
    return (size_t)(span * 4096 + 2048) * 3072 + (size_t)rem * 1536;
}

__device__ __forceinline__ int lower_bound(const int* __restrict__ a, int lo, int hi, int v) {
    while (lo < hi) {
        int mid = (lo + hi) >> 1;
        if (a[mid] < v) lo = mid + 1; else hi = mid;
    }
    return lo;
}

// -------- kernel 1: fused meta+keep (+wprep role blocks) --------
// Blocks [0,128): one thread per (b,c), idx = c*8+b so the 8 rows of a chunk
// form an 8-lane subgroup -> keep via shfl_xor OR. Writes counts2/starts2
// (c*8+b layout), masked masks, act, and per-block num/den partials.
// Blocks [128,272): W[k][n] -> wt[n][k] bf16 via LDS 64x64 transpose.
__global__ void fused_meta_kernel(const int* __restrict__ seg,
                                  const int* __restrict__ padm,
                                  const int* __restrict__ regm,
                                  const int* __restrict__ spm,
                                  const float* __restrict__ Wm,
                                  u16* __restrict__ wt,
                                  int* __restrict__ counts2, int* __restrict__ starts2,
                                  int* __restrict__ act,
                                  float* __restrict__ out_mp, float* __restrict__ out_mr,
                                  float* __restrict__ out_sp,
                                  float2* __restrict__ partials) {
    __shared__ float shm[64 * 65 + 8];
    int blk = blockIdx.x;
    int t = threadIdx.x;
    if (blk >= META_BLOCKS) {                    // ---- wprep role ----
        int wb = blk - META_BLOCKS;
        int bk = wb % 12, bn = wb / 12;
        int k0 = bk * 64, n0 = bn * 64;
        int ln = t & 63, lw = t >> 6;
        #pragma unroll
        for (int p = 0; p < 16; ++p) {
            int kl = lw + p * 4;
            shm[kl * 65 + ln] = Wm[(size_t)(k0 + kl) * D_ + n0 + ln];  // coalesced over n
        }
        __syncthreads();
        #pragma unroll
        for (int p = 0; p < 16; ++p) {
            int nl = lw + p * 4;
            wt[(size_t)(n0 + nl) * D_ + k0 + ln] = f2bf(shm[ln * 65 + nl]);
        }
        return;
    }
    // ---- meta role ----
    int idx = blk * 256 + t;                     // [0, M_)
    int c = idx >> 3, b = idx & 7;
    const int* row = seg + b * L_;
    int s = lower_bound(row, 0, L_, c);
    int e = lower_bound(row, s, L_, c + 1);
    int cnt = e - s;
    counts2[idx] = cnt;
    starts2[idx] = s;
    int mp = 0, mr = 0;
    if (cnt > 0) { mp = padm[b * L_ + s]; mr = regm[b * L_ + s]; }
    int sp = (mp == 0) ? -1 : spm[b * L_ + s];
    int k = mp;                                  // keep = OR of mp over the 8 b's
    k |= __shfl_xor(k, 1);
    k |= __shfl_xor(k, 2);
    k |= __shfl_xor(k, 4);
    k = k ? 1 : 0;
    out_mp[b * NC_ + c] = (float)mp;             // mp*keep == mp (keep=0 -> all mp=0)
    out_mr[b * NC_ + c] = (float)(k ? mr : 0);
    out_sp[b * NC_ + c] = (float)(k ? sp : 0);
    if (c < NCH_) act[b * NCH_ + c] = (k && cnt > 0) ? 1 : 0;
    float numP = (float)(k * mr);                // sum(mask_regular_o)
    float denP = (float)(cnt * mr);              // sum(regular_tokens_mask)
    #pragma unroll
    for (int off = 32; off; off >>= 1) {
        numP += __shfl_down(numP, off);
        denP += __shfl_down(denP, off);
    }
    __syncthreads();
    if ((t & 63) == 0) { shm[(t >> 6) * 2] = numP; shm[(t >> 6) * 2 + 1] = denP; }
    __syncthreads();
    if (t == 0)
        partials[blk] = make_float2(shm[0] + shm[2] + shm[4] + shm[6],
                                    shm[1] + shm[3] + shm[5] + shm[7]);
}

// -------- kernel 2: mean -> bf16 A-plane; + zero spans 4-7; + rate --------
__global__ void mean_kernel(const float* __restrict__ x,
                            const int* __restrict__ counts2,
                            const int* __restrict__ starts2,
                            char* __restrict__ outb,
                            const float2* __restrict__ partials,
                            float* __restrict__ rateOut) {
    __shared__ float rbuf[4];
    int mc = blockIdx.x;
    int t = threadIdx.x;                 // 0..191
    if (mc == MC_ + MEAN_ZB) {           // ---- rate role (1 block) ----
        float n = 0.f, d = 0.f;
        if (t < META_BLOCKS) { float2 p = partials[t]; n = p.x; d = p.y; }
        #pragma unroll
        for (int off = 32; off; off >>= 1) { n += __shfl_down(n, off); d += __shfl_down(d, off); }
        if (t < META_BLOCKS && (t & 63) == 0) { rbuf[(t >> 6) * 2] = n; rbuf[(t >> 6) * 2 + 1] = d; }
        __syncthreads();
        if (t == 0) rateOut[0] = (rbuf[0] + rbuf[2]) / (rbuf[1] + rbuf[3]);
        return;
    }
    if (mc >= MC_) {                     // ---- zero role: spans 4..7 (25.2 MB) ----
        int z = mc - MC_;                // 0..511
        int sp = z >> 7;
        size_t base = (size_t)((4 + sp) * 4096 + 2048) * 3072 + (size_t)(z & 127) * 49152;
        float4* p = (float4*)(outb + base);
        float4 zz = make_float4(0.f, 0.f, 0.f, 0.f);
        #pragma unroll
        for (int i = 0; i < 16; ++i) p[t + i * 192] = zz;
        return;
    }
    int b = mc >> 11, c = mc & (NCH_ - 1);
    int idx = c * 8 + b;
    int cnt = counts2[idx], s = starts2[idx];
    float ax = 0.f, ay = 0.f, az = 0.f, aw = 0.f;
    if (cnt > 0) {
        const float4* base = (const float4*)(x + ((size_t)b * L_ + s) * D_) + t;
        for (int tk = 0; tk < cnt; ++tk) {
            float4 v = base[tk * 192];
            ax += v.x; ay += v.y; az += v.z; aw += v.w;
        }
        float inv = 1.f / (float)cnt;
        ax *= inv; ay *= inv; az *= inv; aw *= inv;
    }
    u16* hi = (u16*)(outb + aplane_byte(mc));
    ushort4 h;
    h.x = f2bf(ax); h.y = f2bf(ay); h.z = f2bf(az); h.w = f2bf(aw);
    *(ushort4*)(hi + 4 * t) = h;
}

// -------- kernel 3: 128x384 deep-pipelined MFMA GEMM, 256 blocks (1/CU) ----
// BK=32, 4 LDS buffers/operand, staging 2 K-tiles ahead -> vmcnt(4) counted,
// one raw s_barrier per K-tile, 2 phases x 12 MFMA with setprio. Per K-tile:
// exactly 4 global_load_lds (1 A + 3 B). Slot-XOR LDS swizzle, pre-applied
// on the global source (both-sides rule).
__global__ __launch_bounds__(512, 2) void gemm8_kernel(
        const char* __restrict__ aBytes,          // d_out bytes (A plane)
        const u16* __restrict__ wt,               // [768][768] transposed bf16
        const float* __restrict__ bias,
        const int* __restrict__ act,
        float* __restrict__ out) {
    __shared__ char sA[4 * 8192];                 // 32 KB: 4 bufs x 128 rows x 64 B
    __shared__ char sB[4 * 24576];                // 96 KB: 4 bufs x 384 rows x 64 B
    int bid = blockIdx.x;
    int wg = (bid & 7) * 32 + (bid >> 3);         // XCD-chunked (256 = 8*32)
    int mtile = wg >> 1, ntile = wg & 1;
    int m0 = mtile << 7, n0 = ntile * 384;
    int t = threadIdx.x;
    int lane = t & 63, w = t >> 6;
    int wm = w >> 2, wn = w & 3;                  // 2x4 wave grid; wave owns 64x96

    const char* aT = aBytes + aplane_byte(m0);               // row stride 1536 B
    const char* bT = (const char*)(wt + (size_t)n0 * D_);    // row stride 1536 B

    // staging source offsets (inverse-swizzled). A: i=t (128 rows).
    // B: i = t + j*512, j=0..2 (384 rows).
    int rA = t >> 2, sA_ = t & 3;
    int srcA = rA * 1536 + ((sA_ ^ ((rA ^ (rA >> 2)) & 3)) << 4);
    int srcB[3];
    #pragma unroll
    for (int j = 0; j < 3; ++j) {
        int i = t + j * 512;
        int r = i >> 2, s = i & 3;
        srcB[j] = r * 1536 + ((s ^ ((r ^ (r >> 2)) & 3)) << 4);
    }
    int db = w * 1024;                            // wave-uniform LDS dest base

    // fragment read offsets (swizzled, loop-invariant)
    int aoff[4], boff[6];
    #pragma unroll
    for (int f = 0; f < 4; ++f) {
        int r = wm * 64 + f * 16 + (lane & 15);
        aoff[f] = r * 64 + ((((lane >> 4)) ^ ((r ^ (r >> 2)) & 3)) << 4);
    }
    #pragma unroll
    for (int g = 0; g < 6; ++g) {
        int r = wn * 96 + g * 16 + (lane & 15);
        boff[g] = r * 64 + ((((lane >> 4)) ^ ((r ^ (r >> 2)) & 3)) << 4);
    }

    f32x4 acc[4][6] = {};

    // prologue: stage K-tiles 0,1 (A then B0,B1,B2 -> 4 loads per tile)
    #pragma unroll
    for (int p = 0; p < 2; ++p) {
        int kof = p << 6;
        gload16(aT + srcA + kof, sA + p * 8192 + db);
        #pragma unroll
        for (int j = 0; j < 3; ++j)
            gload16(bT + srcB[j] + kof, sB + p * 24576 + j * 8192 + db);
    }

    #pragma unroll 1
    for (int kt = 0; kt < NKT_; ++kt) {
        // tile kt's 4 loads are oldest; at most 4 newer (tile kt+1) in flight
        if (kt < NKT_ - 1) asm volatile("s_waitcnt vmcnt(4)" ::: "memory");
        else               asm volatile("s_waitcnt vmcnt(0)" ::: "memory");
        __builtin_amdgcn_s_barrier();
        __builtin_amdgcn_sched_barrier(0);
        const char* curA = sA + (kt & 3) * 8192;
        const char* curB = sB + (kt & 3) * 24576;
        int kn = kt + 2;
        int kof = kn << 6;
        // ---- phase A: A-frags + B-frags g0-2, stage A(kn)+B0(kn), 12 MFMA ----
        short8 afr[4], bfr[3];
        #pragma unroll
        for (int f = 0; f < 4; ++f) afr[f] = *(const short8*)(curA + aoff[f]);
        #pragma unroll
        for (int g = 0; g < 3; ++g) bfr[g] = *(const short8*)(curB + boff[g]);
        if (kn < NKT_) {
            gload16(aT + srcA + kof, sA + (kn & 3) * 8192 + db);      // read at kt-2: free
            gload16(bT + srcB[0] + kof, sB + (kn & 3) * 24576 + db);
        }
        __builtin_amdgcn_s_setprio(1);
        #pragma unroll
        for (int f = 0; f < 4; ++f)
            #pragma unroll
            for (int g = 0; g < 3; ++g)
                acc[f][g] = __builtin_amdgcn_mfma_f32_16x16x32_bf16(
                    afr[f], bfr[g], acc[f][g], 0, 0, 0);
        __builtin_amdgcn_s_setprio(0);
        // ---- phase B: B-frags g3-5, stage B1,B2(kn), 12 MFMA ----
        short8 bfr2[3];
        #pragma unroll
        for (int g = 0; g < 3; ++g) bfr2[g] = *(const short8*)(curB + boff[g + 3]);
        if (kn < NKT_) {
            gload16(bT + srcB[1] + kof, sB + (kn & 3) * 24576 + 8192 + db);
            gload16(bT + srcB[2] + kof, sB + (kn & 3) * 24576 + 16384 + db);
        }
        __builtin_amdgcn_s_setprio(1);
        #pragma unroll
        for (int f = 0; f < 4; ++f)
            #pragma unroll
            for (int g = 0; g < 3; ++g)
                acc[f][g + 3] = __builtin_amdgcn_mfma_f32_16x16x32_bf16(
                    afr[f], bfr2[g], acc[f][g + 3], 0, 0, 0);
        __builtin_amdgcn_s_setprio(0);
        __builtin_amdgcn_sched_barrier(0);
    }

    // epilogue: C/D lane map col=lane&15, row=(lane>>4)*4+reg
    int ncol[6]; float bs[6];
    #pragma unroll
    for (int g = 0; g < 6; ++g) {
        ncol[g] = n0 + wn * 96 + g * 16 + (lane & 15);
        bs[g] = bias[ncol[g]];
    }
    #pragma unroll
    for (int f = 0; f < 4; ++f) {
        int rbase = m0 + wm * 64 + f * 16 + ((lane >> 4) << 2);
        #pragma unroll
        for (int q = 0; q < 4; ++q) {
            int mc = rbase + q;
            int av = act[mc];
            int gr = mc + ((mc >> 11) << 11);      // b*4096 + c
            size_t orow = (size_t)gr * D_;
            #pragma unroll
            for (int g = 0; g < 6; ++g) {
                float v = av ? tanh_fast(acc[f][g][q] + bs[g]) : 0.f;
                out[orow + ncol[g]] = v;
            }
        }
    }
}

// -------- kernel 4: zero spans 0-3 (A-plane) AFTER gemm --------
__global__ void zfill0_kernel(char* __restrict__ outb) {
    int z = blockIdx.x;                  // 0..1535
    int sp = z / 384;
    size_t base = (size_t)(sp * 4096 + 2048) * 3072 + (size_t)(z % 384) * 16384;
    float4* p = (float4*)(outb + base);
    float4 zz = make_float4(0.f, 0.f, 0.f, 0.f);
    int t = threadIdx.x;
    #pragma unroll
    for (int i = 0; i < 4; ++i) p[t + i * 256] = zz;
}

extern "C" void kernel_launch(void* const* d_in, const int* in_sizes, int n_in,
                              void* d_out, int out_size, void* d_ws, size_t ws_size,
                              hipStream_t stream) {
    const float* x    = (const float*)d_in[0];
    const int*   seg  = (const int*)d_in[1];
    const int*   padm = (const int*)d_in[2];
    const int*   regm = (const int*)d_in[3];
    const int*   spm  = (const int*)d_in[4];
    const float* Wm   = (const float*)d_in[5];
    const float* bias = (const float*)d_in[6];
    float* out = (float*)d_out;

    char* ws = (char*)d_ws;
    float2* partials = (float2*)ws;               // [128]
    int* counts2 = (int*)(ws + 1024);             // [M_] (c*8+b)
    int* starts2 = counts2 + M_;
    int* act     = starts2 + M_;                  // [MC_]
    u16* wt      = (u16*)(act + MC_);             // 768*768 u16, 16B-aligned

    float* out_mp = out + (size_t)M_ * D_;
    float* out_mr = out_mp + M_;
    float* out_sp = out_mr + M_;
    float* out_rate = out_sp + M_;

    fused_meta_kernel<<<META_BLOCKS + WPREP_BLOCKS, 256, 0, stream>>>(
        seg, padm, regm, spm, Wm, wt, counts2, starts2, act,
        out_mp, out_mr, out_sp, partials);
    mean_kernel<<<MC_ + MEAN_ZB + 1, 192, 0, stream>>>(
        x, counts2, starts2, (char*)d_out, partials, out_rate);
    gemm8_kernel<<<GEMM_BLOCKS, 512, 0, stream>>>(
        (const char*)d_out, wt, bias, act, out);
    zfill0_kernel<<<1536, 256, 0, stream>>>((char*)d_out);
}

// Round 8
// 71.579 us; speedup vs baseline: 4.8153x; 1.1433x over previous
//
#include <hip/hip_runtime.h>
#include <math.h>

#define B_   8
#define L_   4096
#define D_   768
#define NC_  4096
#define NCH_ 2048
#define M_   (B_*NC_)    // 32768 (b,c) pairs
#define MC_  (B_*NCH_)   // 16384 active compact rows
#define NKT_ 24          // K-tiles of 32 (K=768)
#define META_BLOCKS 128
#define WPREP_BLOCKS 144
#define GEMM_BLOCKS 256  // 256 mtiles (BM=64) x 1 ntile (BN=768)
#define MEAN_ZB 512      // zero-role blocks in mean grid (spans 4..7)

typedef __attribute__((ext_vector_type(8))) short short8;
typedef __attribute__((ext_vector_type(4))) float f32x4;
typedef unsigned int u32;
typedef unsigned short u16;

__device__ __forceinline__ void gload16(const void* g, void* l) {
    __builtin_amdgcn_global_load_lds((const __attribute__((address_space(1))) u32*)g,
                                     (__attribute__((address_space(3))) u32*)l, 16, 0, 0);
}

__device__ __forceinline__ u16 f2bf(float f) {           // RNE bf16
    union { float f; u32 u; } v; v.f = f;
    u32 r = v.u + 0x7fffu + ((v.u >> 16) & 1u);
    return (u16)(r >> 16);
}

// tanh(x) = 1 - 2/(e^{2x}+1). Saturates to +-1.
__device__ __forceinline__ float tanh_fast(float x) {
    float e = __builtin_amdgcn_exp2f(x * 2.885390081777927f);
    return 1.f - 2.f * __builtin_amdgcn_rcpf(e + 1.f);
}

// A-plane (bf16 of mean) lives in d_out's dead rows (c>=2048), spans 0..3.
__device__ __forceinline__ size_t aplane_byte(int mc) {
    int span = mc >> 12;
    int rem  = mc & 4095;
    return (size_t)(span * 4096 + 2048) * 3072 + (size_t)rem * 1536;
}

__device__ __forceinline__ int lower_bound(const int* __restrict__ a, int lo, int hi, int v) {
    while (lo < hi) {
        int mid = (lo + hi) >> 1;
        if (a[mid] < v) lo = mid + 1; else hi = mid;
    }
    return lo;
}

// -------- kernel 1: fused meta+keep (+wprep role blocks) --------
__global__ void fused_meta_kernel(const int* __restrict__ seg,
                                  const int* __restrict__ padm,
                                  const int* __restrict__ regm,
                                  const int* __restrict__ spm,
                                  const float* __restrict__ Wm,
                                  u16* __restrict__ wt,
                                  int* __restrict__ counts2, int* __restrict__ starts2,
                                  int* __restrict__ act,
                                  float* __restrict__ out_mp, float* __restrict__ out_mr,
                                  float* __restrict__ out_sp,
                                  float2* __restrict__ partials) {
    __shared__ float shm[64 * 65 + 8];
    int blk = blockIdx.x;
    int t = threadIdx.x;
    if (blk >= META_BLOCKS) {                    // ---- wprep role ----
        int wb = blk - META_BLOCKS;
        int bk = wb % 12, bn = wb / 12;
        int k0 = bk * 64, n0 = bn * 64;
        int ln = t & 63, lw = t >> 6;
        #pragma unroll
        for (int p = 0; p < 16; ++p) {
            int kl = lw + p * 4;
            shm[kl * 65 + ln] = Wm[(size_t)(k0 + kl) * D_ + n0 + ln];  // coalesced over n
        }
        __syncthreads();
        #pragma unroll
        for (int p = 0; p < 16; ++p) {
            int nl = lw + p * 4;
            wt[(size_t)(n0 + nl) * D_ + k0 + ln] = f2bf(shm[ln * 65 + nl]);
        }
        return;
    }
    // ---- meta role ----
    int idx = blk * 256 + t;                     // [0, M_)
    int c = idx >> 3, b = idx & 7;
    const int* row = seg + b * L_;
    int s = lower_bound(row, 0, L_, c);
    int e = lower_bound(row, s, L_, c + 1);
    int cnt = e - s;
    counts2[idx] = cnt;
    starts2[idx] = s;
    int mp = 0, mr = 0;
    if (cnt > 0) { mp = padm[b * L_ + s]; mr = regm[b * L_ + s]; }
    int sp = (mp == 0) ? -1 : spm[b * L_ + s];
    int k = mp;                                  // keep = OR of mp over the 8 b's
    k |= __shfl_xor(k, 1);
    k |= __shfl_xor(k, 2);
    k |= __shfl_xor(k, 4);
    k = k ? 1 : 0;
    out_mp[b * NC_ + c] = (float)mp;             // mp*keep == mp
    out_mr[b * NC_ + c] = (float)(k ? mr : 0);
    out_sp[b * NC_ + c] = (float)(k ? sp : 0);
    if (c < NCH_) act[b * NCH_ + c] = (k && cnt > 0) ? 1 : 0;
    float numP = (float)(k * mr);
    float denP = (float)(cnt * mr);
    #pragma unroll
    for (int off = 32; off; off >>= 1) {
        numP += __shfl_down(numP, off);
        denP += __shfl_down(denP, off);
    }
    __syncthreads();
    if ((t & 63) == 0) { shm[(t >> 6) * 2] = numP; shm[(t >> 6) * 2 + 1] = denP; }
    __syncthreads();
    if (t == 0)
        partials[blk] = make_float2(shm[0] + shm[2] + shm[4] + shm[6],
                                    shm[1] + shm[3] + shm[5] + shm[7]);
}

// -------- kernel 2: mean -> bf16 A-plane; + zero spans 4-7; + rate --------
__global__ void mean_kernel(const float* __restrict__ x,
                            const int* __restrict__ counts2,
                            const int* __restrict__ starts2,
                            char* __restrict__ outb,
                            const float2* __restrict__ partials,
                            float* __restrict__ rateOut) {
    __shared__ float rbuf[4];
    int mc = blockIdx.x;
    int t = threadIdx.x;                 // 0..191
    if (mc == MC_ + MEAN_ZB) {           // ---- rate role (1 block) ----
        float n = 0.f, d = 0.f;
        if (t < META_BLOCKS) { float2 p = partials[t]; n = p.x; d = p.y; }
        #pragma unroll
        for (int off = 32; off; off >>= 1) { n += __shfl_down(n, off); d += __shfl_down(d, off); }
        if (t < META_BLOCKS && (t & 63) == 0) { rbuf[(t >> 6) * 2] = n; rbuf[(t >> 6) * 2 + 1] = d; }
        __syncthreads();
        if (t == 0) rateOut[0] = (rbuf[0] + rbuf[2]) / (rbuf[1] + rbuf[3]);
        return;
    }
    if (mc >= MC_) {                     // ---- zero role: spans 4..7 (25.2 MB) ----
        int z = mc - MC_;                // 0..511
        int sp = z >> 7;
        size_t base = (size_t)((4 + sp) * 4096 + 2048) * 3072 + (size_t)(z & 127) * 49152;
        float4* p = (float4*)(outb + base);
        float4 zz = make_float4(0.f, 0.f, 0.f, 0.f);
        #pragma unroll
        for (int i = 0; i < 16; ++i) p[t + i * 192] = zz;
        return;
    }
    int b = mc >> 11, c = mc & (NCH_ - 1);
    int idx = c * 8 + b;
    int cnt = counts2[idx], s = starts2[idx];
    float ax = 0.f, ay = 0.f, az = 0.f, aw = 0.f;
    if (cnt > 0) {
        const float4* base = (const float4*)(x + ((size_t)b * L_ + s) * D_) + t;
        for (int tk = 0; tk < cnt; ++tk) {
            float4 v = base[tk * 192];
            ax += v.x; ay += v.y; az += v.z; aw += v.w;
        }
        float inv = 1.f / (float)cnt;
        ax *= inv; ay *= inv; az *= inv; aw *= inv;
    }
    u16* hi = (u16*)(outb + aplane_byte(mc));
    ushort4 h;
    h.x = f2bf(ax); h.y = f2bf(ay); h.z = f2bf(az); h.w = f2bf(aw);
    *(ushort4*)(hi + 4 * t) = h;
}

// -------- kernel 3: 64x768 deep-pipelined MFMA GEMM + self-zeroing --------
// One ntile: block owns ALL 768 output cols for its 64 rows -> sole reader of
// its A region -> zeroes it in the epilogue (no atomics, no extra kernel).
// 3-buffer ring (A 3x4KB + B 3x48KB = 156KB LDS), staging 2 K-tiles ahead,
// 7 gload/wave/K-tile (A duplicated across wave halves for uniform vmcnt),
// counted vmcnt(7), one s_barrier per K-tile, 2 phases x 12 MFMA + setprio.
__global__ __launch_bounds__(512, 1) void gemm8_kernel(
        const char* __restrict__ aBytes,          // d_out bytes (A plane)
        const u16* __restrict__ wt,               // [768][768] transposed bf16
        const float* __restrict__ bias,
        const int* __restrict__ act,
        float* __restrict__ out) {
    __shared__ char sAB[159744];                  // A ring 0..12287, B ring 12288..
    char* sA = sAB;
    char* sB = sAB + 12288;
    int bid = blockIdx.x;
    int wg = (bid & 7) * 32 + (bid >> 3);         // XCD-chunked (256 = 8*32)
    int m0 = wg << 6;
    int t = threadIdx.x;
    int lane = t & 63, w = t >> 6;

    const char* aT = aBytes + aplane_byte(m0);    // 64 rows x 1536 B
    const char* bT = (const char*)wt;             // 768 rows x 1536 B

    // A staging src (wave halves duplicate: ta in [0,256))
    int ta = t & 255;
    int rA = ta >> 2, sa = ta & 3;
    int srcA = rA * 1536 + ((sa ^ ((rA ^ (rA >> 2)) & 3)) << 4);
    int dbA = (w & 3) * 1024;
    // B staging src: call j covers rows via i = t + j*512
    int srcB[6];
    #pragma unroll
    for (int j = 0; j < 6; ++j) {
        int i = t + j * 512;
        int r = i >> 2, s = i & 3;
        srcB[j] = r * 1536 + ((s ^ ((r ^ (r >> 2)) & 3)) << 4);
    }
    int dbB = w * 1024;

    // fragment read offsets (swizzled, loop-invariant)
    int aoff[4], boff[6];
    #pragma unroll
    for (int f = 0; f < 4; ++f) {
        int r = f * 16 + (lane & 15);
        aoff[f] = r * 64 + ((((lane >> 4)) ^ ((r ^ (r >> 2)) & 3)) << 4);
    }
    #pragma unroll
    for (int g = 0; g < 6; ++g) {
        int r = w * 96 + g * 16 + (lane & 15);
        boff[g] = r * 64 + ((((lane >> 4)) ^ ((r ^ (r >> 2)) & 3)) << 4);
    }

    f32x4 acc[4][6] = {};

    // prologue: stage K-tiles 0,1 (order per tile: A, B0..B5)
    #pragma unroll
    for (int p = 0; p < 2; ++p) {
        int kof = p << 6;
        gload16(aT + srcA + kof, sA + p * 4096 + dbA);
        #pragma unroll
        for (int j = 0; j < 6; ++j)
            gload16(bT + srcB[j] + kof, sB + p * 49152 + j * 8192 + dbB);
    }

    int cur = 0;
    #pragma unroll 1
    for (int kt = 0; kt < NKT_; ++kt) {
        // tile kt's 7 loads oldest; <=7 newer (tile kt+1) stay in flight
        if (kt < NKT_ - 1) asm volatile("s_waitcnt vmcnt(7)" ::: "memory");
        else               asm volatile("s_waitcnt vmcnt(0)" ::: "memory");
        __builtin_amdgcn_s_barrier();
        __builtin_amdgcn_sched_barrier(0);
        const char* curA = sA + cur * 4096;
        const char* curB = sB + cur * 49152;
        int nxt = cur + 2; if (nxt >= 3) nxt -= 3;
        int kof = (kt + 2) << 6;
        bool st = (kt + 2 < NKT_);
        // ---- phase A: A-frags + B-frags g0-2; stage A,B0,B1,B2; 12 MFMA ----
        short8 afr[4], bfr[3];
        #pragma unroll
        for (int f = 0; f < 4; ++f) afr[f] = *(const short8*)(curA + aoff[f]);
        #pragma unroll
        for (int g = 0; g < 3; ++g) bfr[g] = *(const short8*)(curB + boff[g]);
        if (st) {
            gload16(aT + srcA + kof, sA + nxt * 4096 + dbA);
            gload16(bT + srcB[0] + kof, sB + nxt * 49152 + dbB);
            gload16(bT + srcB[1] + kof, sB + nxt * 49152 + 8192 + dbB);
            gload16(bT + srcB[2] + kof, sB + nxt * 49152 + 16384 + dbB);
        }
        __builtin_amdgcn_s_setprio(1);
        #pragma unroll
        for (int f = 0; f < 4; ++f)
            #pragma unroll
            for (int g = 0; g < 3; ++g)
                acc[f][g] = __builtin_amdgcn_mfma_f32_16x16x32_bf16(
                    afr[f], bfr[g], acc[f][g], 0, 0, 0);
        __builtin_amdgcn_s_setprio(0);
        // ---- phase B: B-frags g3-5; stage B3,B4,B5; 12 MFMA ----
        short8 bfr2[3];
        #pragma unroll
        for (int g = 0; g < 3; ++g) bfr2[g] = *(const short8*)(curB + boff[g + 3]);
        if (st) {
            gload16(bT + srcB[3] + kof, sB + nxt * 49152 + 24576 + dbB);
            gload16(bT + srcB[4] + kof, sB + nxt * 49152 + 32768 + dbB);
            gload16(bT + srcB[5] + kof, sB + nxt * 49152 + 40960 + dbB);
        }
        __builtin_amdgcn_s_setprio(1);
        #pragma unroll
        for (int f = 0; f < 4; ++f)
            #pragma unroll
            for (int g = 0; g < 3; ++g)
                acc[f][g + 3] = __builtin_amdgcn_mfma_f32_16x16x32_bf16(
                    afr[f], bfr2[g], acc[f][g + 3], 0, 0, 0);
        __builtin_amdgcn_s_setprio(0);
        __builtin_amdgcn_sched_barrier(0);
        if (++cur == 3) cur = 0;
    }

    // epilogue: C/D lane map col=lane&15, row=(lane>>4)*4+reg
    int ncol[6]; float bs[6];
    #pragma unroll
    for (int g = 0; g < 6; ++g) {
        ncol[g] = w * 96 + g * 16 + (lane & 15);
        bs[g] = bias[ncol[g]];
    }
    #pragma unroll
    for (int f = 0; f < 4; ++f) {
        int rbase = m0 + f * 16 + ((lane >> 4) << 2);
        #pragma unroll
        for (int q = 0; q < 4; ++q) {
            int mc = rbase + q;
            int av = act[mc];
            int gr = mc + ((mc >> 11) << 11);      // b*4096 + c
            size_t orow = (size_t)gr * D_;
            #pragma unroll
            for (int g = 0; g < 6; ++g) {
                float v = av ? tanh_fast(acc[f][g][q] + bs[g]) : 0.f;
                out[orow + ncol[g]] = v;
            }
        }
    }

    // self-zero: this block is the sole reader of its A region (96 KB)
    float4* pz = (float4*)((char*)out + aplane_byte(m0));
    float4 zz = make_float4(0.f, 0.f, 0.f, 0.f);
    #pragma unroll
    for (int i = 0; i < 12; ++i) pz[t + i * 512] = zz;
}

extern "C" void kernel_launch(void* const* d_in, const int* in_sizes, int n_in,
                              void* d_out, int out_size, void* d_ws, size_t ws_size,
                              hipStream_t stream) {
    const float* x    = (const float*)d_in[0];
    const int*   seg  = (const int*)d_in[1];
    const int*   padm = (const int*)d_in[2];
    const int*   regm = (const int*)d_in[3];
    const int*   spm  = (const int*)d_in[4];
    const float* Wm   = (const float*)d_in[5];
    const float* bias = (const float*)d_in[6];
    float* out = (float*)d_out;

    char* ws = (char*)d_ws;
    float2* partials = (float2*)ws;               // [128]
    int* counts2 = (int*)(ws + 1024);             // [M_] (c*8+b)
    int* starts2 = counts2 + M_;
    int* act     = starts2 + M_;                  // [MC_]
    u16* wt      = (u16*)(act + MC_);             // 768*768 u16, 16B-aligned

    float* out_mp = out + (size_t)M_ * D_;
    float* out_mr = out_mp + M_;
    float* out_sp = out_mr + M_;
    float* out_rate = out_sp + M_;

    fused_meta_kernel<<<META_BLOCKS + WPREP_BLOCKS, 256, 0, stream>>>(
        seg, padm, regm, spm, Wm, wt, counts2, starts2, act,
        out_mp, out_mr, out_sp, partials);
    mean_kernel<<<MC_ + MEAN_ZB + 1, 192, 0, stream>>>(
        x, counts2, starts2, (char*)d_out, partials, out_rate);
    gemm8_kernel<<<GEMM_BLOCKS, 512, 0, stream>>>(
        (const char*)d_out, wt, bias, act, out);
}